// Round 1
// baseline (1839.755 us; speedup 1.0000x reference)
//
#include <hip/hip_runtime.h>

#define BB 32
#define CC 129
#define TT 1000
#define DD 256
#define NN 64
#define NLY 4

// ---------------- workspace layout (floats) ----------------
// h:    [0, 8192000)                      (B,D,T)
// kker: [8192000, 9216000)                (NL,D,T)
// Ad:   [9216000, 9232384)                (NL,64,64)
// invn: [9232384, 9264384)                (B,T)
// mha:  [9264384, ...)  qk(2048) qb(16) sc(262144) att(262144) ctx(65536)
// overlay in h (dead before embed): P(4*33*4096) Q(4*32*4096) L(4*256*32*64) R(same)
#define OFF_H    0
#define OFF_K    8192000
#define OFF_AD   9216000
#define OFF_INV  9232384
#define OFF_MHA  9264384

// ============ Ad = (I - dtA/2)^-1 (I + dtA/2), Gauss-Jordan w/ partial pivot ============
__global__ __launch_bounds__(64) void k_build_ad(const float* __restrict__ logdt,
                                                 float* __restrict__ Ad) {
    __shared__ float M[64][130];
    __shared__ int piv;
    int l = blockIdx.x, r = threadIdx.x;
    float dt = expf(logdt[l * DD]);
    dt = fminf(fmaxf(dt, 1e-4f), 0.1f);
    float hh = dt * 0.5f;
    float Pr = sqrtf(1.f + 2.f * (float)r);
    for (int j = 0; j < 64; ++j) {
        float a;
        if (r == j) a = -((float)r + 0.5f);
        else { float m = Pr * sqrtf(1.f + 2.f * (float)j); a = (r > j) ? -m : m; }
        float dta = hh * a;
        M[r][j]      = ((r == j) ? 1.f : 0.f) - dta;
        M[r][64 + j] = ((r == j) ? 1.f : 0.f) + dta;
    }
    __syncthreads();
    for (int c = 0; c < 64; ++c) {
        if (r == 0) {
            int p = c; float best = fabsf(M[c][c]);
            for (int i = c + 1; i < 64; ++i) {
                float v = fabsf(M[i][c]);
                if (v > best) { best = v; p = i; }
            }
            piv = p;
        }
        __syncthreads();
        int p = piv;
        if (p != c) {
            for (int j = r; j < 130; j += 64) { float t = M[c][j]; M[c][j] = M[p][j]; M[p][j] = t; }
        }
        __syncthreads();
        float pv = M[c][c];
        for (int j = r; j < 130; j += 64) M[c][j] /= pv;
        __syncthreads();
        if (r != c) {
            float f = M[r][c];
            for (int j = c; j < 130; ++j) M[r][j] = fmaf(-f, M[c][j], M[r][j]);
        }
        __syncthreads();
    }
    for (int j = 0; j < 64; ++j) Ad[(l * 64 + r) * 64 + j] = M[r][64 + j];
}

// ============ power tree ============
__global__ __launch_bounds__(256) void k_pq_init(const float* __restrict__ Ad, float* __restrict__ P) {
    int l = blockIdx.x;
    for (int i = threadIdx.x; i < 4096; i += 256) {
        int r = i >> 6, c = i & 63;
        P[(l * 33 + 0) * 4096 + i] = (r == c) ? 1.f : 0.f;
        P[(l * 33 + 1) * 4096 + i] = Ad[l * 4096 + i];
    }
}

__global__ __launch_bounds__(256) void k_q_init(const float* __restrict__ P, float* __restrict__ Q) {
    int l = blockIdx.x;
    for (int i = threadIdx.x; i < 4096; i += 256) {
        int r = i >> 6, c = i & 63;
        Q[(l * 32 + 0) * 4096 + i] = (r == c) ? 1.f : 0.f;
        Q[(l * 32 + 1) * 4096 + i] = P[(l * 33 + 32) * 4096 + i];
    }
}

// D_j = M_half * M_{j-half},  j = half+1+blockIdx.x
__global__ __launch_bounds__(256) void k_mm64(float* __restrict__ base, int half, int smats) {
    __shared__ float As[4096], Bs[4096];
    int l = blockIdx.y;
    int j = half + 1 + blockIdx.x;
    const float* Am = base + (size_t)(l * smats + half) * 4096;
    const float* Bm = base + (size_t)(l * smats + (j - half)) * 4096;
    float* Dm = base + (size_t)(l * smats + j) * 4096;
    for (int i = threadIdx.x; i < 4096; i += 256) { As[i] = Am[i]; Bs[i] = Bm[i]; }
    __syncthreads();
    int tr = (threadIdx.x >> 4) << 2;
    int tc = (threadIdx.x & 15) << 2;
    float acc[4][4];
#pragma unroll
    for (int u = 0; u < 4; ++u)
#pragma unroll
        for (int v = 0; v < 4; ++v) acc[u][v] = 0.f;
    for (int k = 0; k < 64; ++k) {
        float a0 = As[(tr + 0) * 64 + k], a1 = As[(tr + 1) * 64 + k];
        float a2 = As[(tr + 2) * 64 + k], a3 = As[(tr + 3) * 64 + k];
        float b0 = Bs[k * 64 + tc + 0], b1 = Bs[k * 64 + tc + 1];
        float b2 = Bs[k * 64 + tc + 2], b3 = Bs[k * 64 + tc + 3];
        acc[0][0] = fmaf(a0, b0, acc[0][0]); acc[0][1] = fmaf(a0, b1, acc[0][1]);
        acc[0][2] = fmaf(a0, b2, acc[0][2]); acc[0][3] = fmaf(a0, b3, acc[0][3]);
        acc[1][0] = fmaf(a1, b0, acc[1][0]); acc[1][1] = fmaf(a1, b1, acc[1][1]);
        acc[1][2] = fmaf(a1, b2, acc[1][2]); acc[1][3] = fmaf(a1, b3, acc[1][3]);
        acc[2][0] = fmaf(a2, b0, acc[2][0]); acc[2][1] = fmaf(a2, b1, acc[2][1]);
        acc[2][2] = fmaf(a2, b2, acc[2][2]); acc[2][3] = fmaf(a2, b3, acc[2][3]);
        acc[3][0] = fmaf(a3, b0, acc[3][0]); acc[3][1] = fmaf(a3, b1, acc[3][1]);
        acc[3][2] = fmaf(a3, b2, acc[3][2]); acc[3][3] = fmaf(a3, b3, acc[3][3]);
    }
#pragma unroll
    for (int u = 0; u < 4; ++u)
#pragma unroll
        for (int v = 0; v < 4; ++v) Dm[(tr + u) * 64 + tc + v] = acc[u][v];
}

// ============ L[l,d,k,j] = sum_i B[l,i,d] Q_k[i,j];  R[l,d,r,i] = sum_j P_r[i,j] C[l,d,j] ============
__global__ __launch_bounds__(256) void k_lr(const float* __restrict__ P, const float* __restrict__ Q,
                                            const float* __restrict__ s4B, const float* __restrict__ s4C,
                                            float* __restrict__ L, float* __restrict__ R) {
    __shared__ float Ms[4096];
    int l = blockIdx.x >> 6, rem = blockIdx.x & 63, which = rem >> 5, idx = rem & 31;
    const float* M = which ? (P + (size_t)(l * 33 + idx) * 4096)
                           : (Q + (size_t)(l * 32 + idx) * 4096);
    for (int i = threadIdx.x; i < 4096; i += 256) Ms[i] = M[i];
    __syncthreads();
    int d = threadIdx.x;
    if (which == 0) {
        float* dst = L + (((size_t)(l * DD + d) * 32 + idx) * 64);
        for (int jc = 0; jc < 8; ++jc) {
            float acc[8];
#pragma unroll
            for (int u = 0; u < 8; ++u) acc[u] = 0.f;
            for (int i = 0; i < 64; ++i) {
                float bv = s4B[(l * NN + i) * DD + d];
#pragma unroll
                for (int u = 0; u < 8; ++u)
                    acc[u] = fmaf(bv, Ms[i * 64 + jc * 8 + u], acc[u]);
            }
#pragma unroll
            for (int u = 0; u < 8; ++u) dst[jc * 8 + u] = acc[u];
        }
    } else {
        float* dst = R + (((size_t)(l * DD + d) * 32 + idx) * 64);
        const float* Cp = s4C + (size_t)(l * DD + d) * NN;
        for (int ic = 0; ic < 8; ++ic) {
            float acc[8];
#pragma unroll
            for (int u = 0; u < 8; ++u) acc[u] = 0.f;
            for (int j = 0; j < 64; ++j) {
                float cv = Cp[j];
#pragma unroll
                for (int u = 0; u < 8; ++u)
                    acc[u] = fmaf(Ms[(ic * 8 + u) * 64 + j], cv, acc[u]);
            }
#pragma unroll
            for (int u = 0; u < 8; ++u) dst[ic * 8 + u] = acc[u];
        }
    }
}

// ============ k[l,d,t] = decay(t) * dot(L[l,d,t>>5,:], R[l,d,t&31,:]) ============
__global__ __launch_bounds__(256) void k_kker(const float* __restrict__ L, const float* __restrict__ R,
                                              float* __restrict__ kk) {
    __shared__ float Ls[32 * 65], Rs[32 * 65];
    int l = blockIdx.x >> 8, d = blockIdx.x & 255;
    const float* Lp = L + ((size_t)(l * DD + d) * 32) * 64;
    const float* Rp = R + ((size_t)(l * DD + d) * 32) * 64;
    for (int i = threadIdx.x; i < 2048; i += 256) {
        int row = i >> 6, col = i & 63;
        Ls[row * 65 + col] = Lp[i];
        Rs[row * 65 + col] = Rp[i];
    }
    __syncthreads();
    for (int t = threadIdx.x; t < TT; t += 256) {
        int kq = t >> 5, r = t & 31;
        const float* lr = &Ls[kq * 65];
        const float* rr = &Rs[r * 65];
        float a = 0.f;
#pragma unroll 8
        for (int m = 0; m < 64; ++m) a = fmaf(lr[m], rr[m], a);
        kk[(size_t)(l * DD + d) * TT + t] = a * expf(-0.01f * (float)t);
    }
}

// ============ embed: h[b,d,t] = sum_c w_in[d,c] x[b,c,t] + b_in[d] ============
__global__ __launch_bounds__(256) void k_embed(const float* __restrict__ x, const float* __restrict__ w_in,
                                               const float* __restrict__ b_in, float* __restrict__ h) {
    __shared__ float xt[CC][64];
    int b = blockIdx.y, t0 = blockIdx.x * 64;
    for (int i = threadIdx.x; i < CC * 64; i += 256) {
        int c = i >> 6, tl = i & 63;
        int t = t0 + tl;
        xt[c][tl] = (t < TT) ? x[(size_t)(b * CC + c) * TT + t] : 0.f;
    }
    __syncthreads();
    int w = threadIdx.x >> 6, lane = threadIdx.x & 63;
    int t = t0 + lane;
    for (int d0 = w * 64; d0 < w * 64 + 64; d0 += 4) {
        float a0 = b_in[d0], a1 = b_in[d0 + 1], a2 = b_in[d0 + 2], a3 = b_in[d0 + 3];
        for (int c = 0; c < CC; ++c) {
            float xv = xt[c][lane];
            a0 = fmaf(w_in[(d0 + 0) * CC + c], xv, a0);
            a1 = fmaf(w_in[(d0 + 1) * CC + c], xv, a1);
            a2 = fmaf(w_in[(d0 + 2) * CC + c], xv, a2);
            a3 = fmaf(w_in[(d0 + 3) * CC + c], xv, a3);
        }
        if (t < TT) {
            h[(size_t)(b * DD + d0 + 0) * TT + t] = a0;
            h[(size_t)(b * DD + d0 + 1) * TT + t] = a1;
            h[(size_t)(b * DD + d0 + 2) * TT + t] = a2;
            h[(size_t)(b * DD + d0 + 3) * TT + t] = a3;
        }
    }
}

// ============ LayerNorm over d (in-place), optional +pos-encoding ============
__global__ __launch_bounds__(256) void k_ln(const float* __restrict__ in, const float* __restrict__ g,
                                            const float* __restrict__ bia, float* __restrict__ out,
                                            int add_pe) {
    int b = blockIdx.y, t0 = blockIdx.x * 64;
    int w = threadIdx.x >> 6, lane = threadIdx.x & 63;
    int t = t0 + lane;
    __shared__ float ps[4][64], ps2[4][64];
    float s = 0.f, s2 = 0.f;
    if (t < TT)
        for (int d = w; d < DD; d += 4) {
            float v = in[(size_t)(b * DD + d) * TT + t];
            s += v; s2 = fmaf(v, v, s2);
        }
    ps[w][lane] = s; ps2[w][lane] = s2;
    __syncthreads();
    float mean = (ps[0][lane] + ps[1][lane] + ps[2][lane] + ps[3][lane]) * (1.f / 256.f);
    float ex2  = (ps2[0][lane] + ps2[1][lane] + ps2[2][lane] + ps2[3][lane]) * (1.f / 256.f);
    float rstd = 1.f / sqrtf(ex2 - mean * mean + 1e-5f);
    if (t < TT) {
        float ft = (float)t;
        for (int d = w; d < DD; d += 4) {
            size_t ix = (size_t)(b * DD + d) * TT + t;
            float v = in[ix];
            float o = (v - mean) * rstd * g[d] + bia[d];
            if (add_pe) {
                float freq = expf((float)(d & ~1) * (-9.210340371976184f / 256.f));
                float ang = ft * freq;
                o += (d & 1) ? cosf(ang) : sinf(ang);
            }
            out[ix] = o;
        }
    }
}

// ============ inv row norms over d ============
__global__ __launch_bounds__(256) void k_norms(const float* __restrict__ h, float* __restrict__ invn) {
    int b = blockIdx.y, t0 = blockIdx.x * 64;
    int w = threadIdx.x >> 6, lane = threadIdx.x & 63;
    int t = t0 + lane;
    __shared__ float ps2[4][64];
    float s2 = 0.f;
    if (t < TT)
        for (int d = w; d < DD; d += 4) {
            float v = h[(size_t)(b * DD + d) * TT + t];
            s2 = fmaf(v, v, s2);
        }
    ps2[w][lane] = s2;
    __syncthreads();
    if (w == 0 && t < TT) {
        float tot = ps2[0][lane] + ps2[1][lane] + ps2[2][lane] + ps2[3][lane];
        invn[b * TT + t] = 1.f / (sqrtf(tot) + 1e-8f);
    }
}

__device__ __forceinline__ float gelu_exact(float y) {
    return 0.5f * y * (1.f + erff(y * 0.7071067811865476f));
}

// ============ fused causal conv + gate + gelu + residual, in-place on h ============
__global__ __launch_bounds__(256) void k_conv(float* __restrict__ h, const float* __restrict__ kk,
                                              const float* __restrict__ invn, const float* __restrict__ s4D,
                                              int layer) {
    __shared__ __align__(16) float xs[2048];
    __shared__ __align__(16) float ks[1024];
    __shared__ float hr[1024];
    int d = blockIdx.x, b = blockIdx.y;
    int tid = threadIdx.x;
    float* hrow = h + (size_t)(b * DD + d) * TT;
    const float* krow = kk + (size_t)(layer * DD + d) * TT;
    for (int m = tid; m < 1024; m += 256) xs[m] = 0.f;
    for (int m = tid; m < TT; m += 256) {
        float v = hrow[m];
        hr[m] = v;
        xs[1024 + m] = v * invn[b * TT + m];
        ks[m] = krow[m];
    }
    __syncthreads();
    if (tid < 250) {
        const float4* xs4 = (const float4*)xs;
        const float4* ks4 = (const float4*)ks;
        int t0 = tid * 4;
        int base = (1024 + t0) >> 2;
        float acc0 = 0.f, acc1 = 0.f, acc2 = 0.f, acc3 = 0.f;
        float4 hi = xs4[base];
        int tmaxw = (tid | 63); if (tmaxw > 249) tmaxw = 249;
        int iters = tmaxw + 1;   // wave-uniform
        for (int s4 = 0; s4 < iters; ++s4) {
            float4 lo = xs4[base - s4 - 1];
            float4 k4 = ks4[s4];
            acc0 = fmaf(k4.x, hi.x, acc0); acc0 = fmaf(k4.y, lo.w, acc0);
            acc0 = fmaf(k4.z, lo.z, acc0); acc0 = fmaf(k4.w, lo.y, acc0);
            acc1 = fmaf(k4.x, hi.y, acc1); acc1 = fmaf(k4.y, hi.x, acc1);
            acc1 = fmaf(k4.z, lo.w, acc1); acc1 = fmaf(k4.w, lo.z, acc1);
            acc2 = fmaf(k4.x, hi.z, acc2); acc2 = fmaf(k4.y, hi.y, acc2);
            acc2 = fmaf(k4.z, hi.x, acc2); acc2 = fmaf(k4.w, lo.w, acc2);
            acc3 = fmaf(k4.x, hi.w, acc3); acc3 = fmaf(k4.y, hi.z, acc3);
            acc3 = fmaf(k4.z, hi.y, acc3); acc3 = fmaf(k4.w, hi.x, acc3);
            hi = lo;
        }
        float gate = 1.f / (1.f + expf(-s4D[layer * DD + d]));
        float o0 = gelu_exact(acc0 + xs[1024 + t0 + 0] * gate) + 1.1f * hr[t0 + 0];
        float o1 = gelu_exact(acc1 + xs[1024 + t0 + 1] * gate) + 1.1f * hr[t0 + 1];
        float o2 = gelu_exact(acc2 + xs[1024 + t0 + 2] * gate) + 1.1f * hr[t0 + 2];
        float o3 = gelu_exact(acc3 + xs[1024 + t0 + 3] * gate) + 1.1f * hr[t0 + 3];
        float4 o4; o4.x = o0; o4.y = o1; o4.z = o2; o4.w = o3;
        ((float4*)hrow)[tid] = o4;
    }
}

// ============ MHA pooling ============
__global__ __launch_bounds__(256) void k_qprep(const float* __restrict__ cls, const float* __restrict__ inw,
                                               const float* __restrict__ inb, float* __restrict__ qk,
                                               float* __restrict__ qb) {
    __shared__ float Qv[256];
    int j = threadIdx.x;
    float a = inb[j];
    for (int i = 0; i < 256; ++i) a = fmaf(inw[j * DD + i], cls[i], a);
    Qv[j] = a;
    __syncthreads();
    const float scale = 0.17677669529663687f; // 1/sqrt(32)
    for (int idx = threadIdx.x; idx < 8 * 256; idx += 256) {
        int hh = idx >> 8, i = idx & 255;
        float s = 0.f;
        for (int jj = 0; jj < 32; ++jj)
            s = fmaf(Qv[hh * 32 + jj], inw[(DD + hh * 32 + jj) * DD + i], s);
        qk[idx] = s * scale;
    }
    if (threadIdx.x < 8) {
        int hh = threadIdx.x;
        float s = 0.f;
        for (int jj = 0; jj < 32; ++jj)
            s = fmaf(Qv[hh * 32 + jj], inb[DD + hh * 32 + jj], s);
        qb[hh] = s * scale;
    }
}

__global__ __launch_bounds__(256) void k_scores(const float* __restrict__ h, const float* __restrict__ cls,
                                                const float* __restrict__ qkw, const float* __restrict__ qbw,
                                                float* __restrict__ sc) {
    __shared__ float qks[8 * 256];
    int b = blockIdx.y;
    int s = blockIdx.x * 256 + threadIdx.x;
    for (int i = threadIdx.x; i < 2048; i += 256) qks[i] = qkw[i];
    __syncthreads();
    if (s >= TT + 1) return;
    float acc[8];
#pragma unroll
    for (int hh = 0; hh < 8; ++hh) acc[hh] = qbw[hh];
    if (s == 0) {
        for (int i = 0; i < 256; ++i) {
            float v = cls[i];
#pragma unroll
            for (int hh = 0; hh < 8; ++hh) acc[hh] = fmaf(qks[hh * 256 + i], v, acc[hh]);
        }
    } else {
        const float* hb = h + (size_t)b * DD * TT + (s - 1);
        for (int i = 0; i < 256; ++i) {
            float v = hb[(size_t)i * TT];
#pragma unroll
            for (int hh = 0; hh < 8; ++hh) acc[hh] = fmaf(qks[hh * 256 + i], v, acc[hh]);
        }
    }
#pragma unroll
    for (int hh = 0; hh < 8; ++hh) sc[(size_t)(b * 8 + hh) * 1024 + s] = acc[hh];
}

__global__ __launch_bounds__(256) void k_softmax(const float* __restrict__ sc, float* __restrict__ att) {
    int row = blockIdx.x;
    const float* p = sc + (size_t)row * 1024;
    float* o = att + (size_t)row * 1024;
    __shared__ float red[256];
    float m = -3.4e38f;
    for (int s = threadIdx.x; s < TT + 1; s += 256) m = fmaxf(m, p[s]);
    red[threadIdx.x] = m; __syncthreads();
    for (int st = 128; st; st >>= 1) {
        if (threadIdx.x < st) red[threadIdx.x] = fmaxf(red[threadIdx.x], red[threadIdx.x + st]);
        __syncthreads();
    }
    m = red[0]; __syncthreads();
    float sum = 0.f;
    for (int s = threadIdx.x; s < TT + 1; s += 256) {
        float e = expf(p[s] - m);
        o[s] = e; sum += e;
    }
    red[threadIdx.x] = sum; __syncthreads();
    for (int st = 128; st; st >>= 1) {
        if (threadIdx.x < st) red[threadIdx.x] += red[threadIdx.x + st];
        __syncthreads();
    }
    float inv = 1.f / red[0];
    for (int s = threadIdx.x; s < TT + 1; s += 256) o[s] *= inv;
}

__global__ __launch_bounds__(256) void k_ctx(const float* __restrict__ h, const float* __restrict__ cls,
                                             const float* __restrict__ att, float* __restrict__ ctx) {
    __shared__ float as[8][1024];
    int b = blockIdx.y, i0 = blockIdx.x * 32;
    for (int idx = threadIdx.x; idx < 8 * 1024; idx += 256) {
        int hh = idx >> 10, s = idx & 1023;
        as[hh][s] = (s < TT + 1) ? att[(size_t)(b * 8 + hh) * 1024 + s] : 0.f;
    }
    __syncthreads();
    int w = threadIdx.x >> 6, lane = threadIdx.x & 63;
    for (int ii = 0; ii < 8; ++ii) {
        int i = i0 + w * 8 + ii;
        const float* hb = h + (size_t)(b * DD + i) * TT;
        float acc[8];
#pragma unroll
        for (int hh = 0; hh < 8; ++hh) acc[hh] = 0.f;
        for (int t = lane; t < TT; t += 64) {
            float v = hb[t];
#pragma unroll
            for (int hh = 0; hh < 8; ++hh) acc[hh] = fmaf(as[hh][t + 1], v, acc[hh]);
        }
#pragma unroll
        for (int off = 32; off; off >>= 1)
#pragma unroll
            for (int hh = 0; hh < 8; ++hh) acc[hh] += __shfl_down(acc[hh], off);
        if (lane == 0) {
#pragma unroll
            for (int hh = 0; hh < 8; ++hh)
                ctx[(size_t)(b * 8 + hh) * DD + i] = acc[hh] + as[hh][0] * cls[i];
        }
    }
}

__global__ __launch_bounds__(256) void k_head(const float* __restrict__ ctx, const float* __restrict__ inw,
                                              const float* __restrict__ inb, const float* __restrict__ outw,
                                              const float* __restrict__ outb, const float* __restrict__ w1,
                                              const float* __restrict__ b1, const float* __restrict__ w2,
                                              const float* __restrict__ b2, float* __restrict__ out) {
    int b = blockIdx.x;
    __shared__ float cs[2048], ao[256], po[256], hid[128];
    for (int i = threadIdx.x; i < 2048; i += 256) cs[i] = ctx[(size_t)b * 2048 + i];
    __syncthreads();
    int j = threadIdx.x;
    {
        int hh = j >> 5;
        float a = inb[2 * DD + j];
        const float* wv = inw + (size_t)(2 * DD + j) * DD;
        for (int i = 0; i < 256; ++i) a = fmaf(wv[i], cs[hh * 256 + i], a);
        ao[j] = a;
    }
    __syncthreads();
    {
        float a = outb[j];
        for (int i = 0; i < 256; ++i) a = fmaf(outw[j * DD + i], ao[i], a);
        po[j] = a;
    }
    __syncthreads();
    if (j < 128) {
        float a = b1[j];
        for (int i = 0; i < 256; ++i) a = fmaf(w1[j * 256 + i], po[i], a);
        hid[j] = fmaxf(a, 0.f);
    }
    __syncthreads();
    if (j == 0) {
        float a = b2[0];
        for (int i = 0; i < 128; ++i) a = fmaf(w2[i], hid[i], a);
        out[b] = a;
    }
}

extern "C" void kernel_launch(void* const* d_in, const int* in_sizes, int n_in,
                              void* d_out, int out_size, void* d_ws, size_t ws_size,
                              hipStream_t stream) {
    (void)in_sizes; (void)n_in; (void)out_size; (void)ws_size;
    const float* x        = (const float*)d_in[0];
    const float* w_in     = (const float*)d_in[1];
    const float* b_in     = (const float*)d_in[2];
    const float* ln_in_g  = (const float*)d_in[3];
    const float* ln_in_b  = (const float*)d_in[4];
    const float* s4B      = (const float*)d_in[5];
    const float* s4C      = (const float*)d_in[6];
    const float* s4logdt  = (const float*)d_in[7];
    const float* s4D      = (const float*)d_in[8];
    const float* ln_g     = (const float*)d_in[9];
    const float* ln_b     = (const float*)d_in[10];
    const float* cls      = (const float*)d_in[11];
    const float* mha_in_w = (const float*)d_in[12];
    const float* mha_in_b = (const float*)d_in[13];
    const float* mha_out_w= (const float*)d_in[14];
    const float* mha_out_b= (const float*)d_in[15];
    const float* head_w1  = (const float*)d_in[16];
    const float* head_b1  = (const float*)d_in[17];
    const float* head_w2  = (const float*)d_in[18];
    const float* head_b2  = (const float*)d_in[19];

    float* ws   = (float*)d_ws;
    float* h    = ws + OFF_H;
    float* kker = ws + OFF_K;
    float* Ad   = ws + OFF_AD;
    float* invn = ws + OFF_INV;
    // overlay power-tree buffers in (currently dead) h region
    float* P  = h;
    float* Q  = h + 540672;
    float* Lb = h + 1064960;
    float* Rb = h + 3162112;
    // MHA scratch
    float* qkb  = ws + OFF_MHA;
    float* qbb  = qkb + 2048;
    float* scb  = qbb + 16;
    float* attb = scb + 262144;
    float* ctxb = attb + 262144;

    k_build_ad<<<dim3(NLY), dim3(64), 0, stream>>>(s4logdt, Ad);
    k_pq_init<<<dim3(NLY), dim3(256), 0, stream>>>(Ad, P);
    for (int m = 1; m <= 5; ++m) {
        int half = 1 << (m - 1);
        k_mm64<<<dim3(half, NLY), dim3(256), 0, stream>>>(P, half, 33);
    }
    k_q_init<<<dim3(NLY), dim3(256), 0, stream>>>(P, Q);
    for (int m = 1; m <= 5; ++m) {
        int half = 1 << (m - 1);
        int cnt = (m == 5) ? 15 : half;
        k_mm64<<<dim3(cnt, NLY), dim3(256), 0, stream>>>(Q, half, 32);
    }
    k_lr<<<dim3(NLY * 64), dim3(256), 0, stream>>>(P, Q, s4B, s4C, Lb, Rb);
    k_kker<<<dim3(NLY * 256), dim3(256), 0, stream>>>(Lb, Rb, kker);

    k_embed<<<dim3(16, BB), dim3(256), 0, stream>>>(x, w_in, b_in, h);
    k_ln<<<dim3(16, BB), dim3(256), 0, stream>>>(h, ln_in_g, ln_in_b, h, 1);

    for (int l = 0; l < NLY; ++l) {
        k_norms<<<dim3(16, BB), dim3(256), 0, stream>>>(h, invn);
        k_conv<<<dim3(DD, BB), dim3(256), 0, stream>>>(h, kker, invn, s4D, l);
        k_ln<<<dim3(16, BB), dim3(256), 0, stream>>>(h, ln_g + l * DD, ln_b + l * DD, h, 0);
    }

    k_qprep<<<dim3(1), dim3(256), 0, stream>>>(cls, mha_in_w, mha_in_b, qkb, qbb);
    k_scores<<<dim3(4, BB), dim3(256), 0, stream>>>(h, cls, qkb, qbb, scb);
    k_softmax<<<dim3(256), dim3(256), 0, stream>>>(scb, attb);
    k_ctx<<<dim3(8, BB), dim3(256), 0, stream>>>(h, cls, attb, ctxb);
    k_head<<<dim3(BB), dim3(256), 0, stream>>>(ctxb, mha_in_w, mha_in_b, mha_out_w, mha_out_b,
                                               head_w1, head_b1, head_w2, head_b2, (float*)d_out);
}

// Round 2
// 1552.653 us; speedup vs baseline: 1.1849x; 1.1849x over previous
//
#include <hip/hip_runtime.h>

#define BB 32
#define CC 129
#define TT 1000
#define DD 256
#define NN 64
#define NLY 4

// ---------------- workspace layout (floats) ----------------
// h:    [0, 8192000)                      (B,D,T)
// kker: [8192000, 9216000)                (NL,D,T)
// Ad:   [9216000, 9232384)                (NL,64,64)
// invn: [9232384, 9264384)                (B,T)
// mha:  [9264384, ...)  qk(2048) qb(16) sc(262144) att(262144) ctx(65536)
// overlay in h (dead before embed): P(4*33*4096) Q(4*32*4096) L(4*256*32*64) R(same)
#define OFF_H    0
#define OFF_K    8192000
#define OFF_AD   9216000
#define OFF_INV  9232384
#define OFF_MHA  9264384

// ============ Ad = (I - dtA/2)^-1 (I + dtA/2), Gauss-Jordan w/ partial pivot ============
// 256 threads: elimination uses (q = tid>>6 column-quarter, r = tid&63 row);
// swap/scale phases use tid as column index. LDS stride 131 (odd) -> 2-way bank
// aliasing only (free). Pivot argmax = wave-0 shfl butterfly.
#define ST 131
__global__ __launch_bounds__(256) void k_build_ad(const float* __restrict__ logdt,
                                                  float* __restrict__ Ad) {
    __shared__ float M[64 * ST];
    __shared__ int piv;
    int l = blockIdx.x;
    int tid = threadIdx.x;
    int q = tid >> 6, r = tid & 63;
    float dt = expf(logdt[l * DD]);
    dt = fminf(fmaxf(dt, 1e-4f), 0.1f);
    float hh = dt * 0.5f;
    float Pr = sqrtf(1.f + 2.f * (float)r);
    // init augmented [I - hh*A | I + hh*A], column-interleaved across quarters
    for (int j = q; j < 130; j += 4) {
        int jj = (j < 64) ? j : (j - 64);
        float a;
        if (r == jj) a = -((float)r + 0.5f);
        else { float m = Pr * sqrtf(1.f + 2.f * (float)jj); a = (r > jj) ? -m : m; }
        float ident = (r == jj) ? 1.f : 0.f;
        M[r * ST + j] = (j < 64) ? (ident - hh * a) : (ident + hh * a);
    }
    __syncthreads();
    for (int c = 0; c < 64; ++c) {
        // --- pivot argmax over rows >= c (wave 0 only) ---
        if (tid < 64) {
            float bv = (r >= c) ? fabsf(M[r * ST + c]) : -1.f;
            int bi = r;
            for (int off = 32; off; off >>= 1) {
                float ov = __shfl_xor(bv, off);
                int oi = __shfl_xor(bi, off);
                if (ov > bv) { bv = ov; bi = oi; }
            }
            if (tid == 0) piv = bi;
        }
        __syncthreads();
        int p = piv;
        // --- swap rows c<->p and scale row c, threads = columns ---
        if (tid >= c && tid < 130) {
            float pv = M[p * ST + c];        // pivot value at pre-swap location
            float inv = 1.f / pv;
            if (p != c) {
                float a = M[c * ST + tid], b2 = M[p * ST + tid];
                M[p * ST + tid] = a;
                M[c * ST + tid] = (tid > c) ? b2 * inv : b2;
            } else if (tid > c) {
                M[c * ST + tid] *= inv;
            }
        }
        __syncthreads();
        // --- eliminate: all rows r != c, cols > c (quarter-interleaved) ---
        if (r != c) {
            float f = M[r * ST + c];
            int base = c + 1;
            int j0 = base + (((q - base) % 4) + 4) % 4;
            for (int j = j0; j < 130; j += 4)
                M[r * ST + j] = fmaf(-f, M[c * ST + j], M[r * ST + j]);
        }
        __syncthreads();
    }
    for (int i = tid; i < 4096; i += 256) {
        int rr = i >> 6, j = i & 63;
        Ad[(l * 64 + rr) * 64 + j] = M[rr * ST + 64 + j];
    }
}

// ============ power tree ============
__global__ __launch_bounds__(256) void k_pq_init(const float* __restrict__ Ad, float* __restrict__ P) {
    int l = blockIdx.x;
    for (int i = threadIdx.x; i < 4096; i += 256) {
        int r = i >> 6, c = i & 63;
        P[(l * 33 + 0) * 4096 + i] = (r == c) ? 1.f : 0.f;
        P[(l * 33 + 1) * 4096 + i] = Ad[l * 4096 + i];
    }
}

__global__ __launch_bounds__(256) void k_q_init(const float* __restrict__ P, float* __restrict__ Q) {
    int l = blockIdx.x;
    for (int i = threadIdx.x; i < 4096; i += 256) {
        int r = i >> 6, c = i & 63;
        Q[(l * 32 + 0) * 4096 + i] = (r == c) ? 1.f : 0.f;
        Q[(l * 32 + 1) * 4096 + i] = P[(l * 33 + 32) * 4096 + i];
    }
}

// D_j = M_half * M_{j-half},  j = half+1+blockIdx.x
__global__ __launch_bounds__(256) void k_mm64(float* __restrict__ base, int half, int smats) {
    __shared__ float As[4096], Bs[4096];
    int l = blockIdx.y;
    int j = half + 1 + blockIdx.x;
    const float* Am = base + (size_t)(l * smats + half) * 4096;
    const float* Bm = base + (size_t)(l * smats + (j - half)) * 4096;
    float* Dm = base + (size_t)(l * smats + j) * 4096;
    for (int i = threadIdx.x; i < 4096; i += 256) { As[i] = Am[i]; Bs[i] = Bm[i]; }
    __syncthreads();
    int tr = (threadIdx.x >> 4) << 2;
    int tc = (threadIdx.x & 15) << 2;
    float acc[4][4];
#pragma unroll
    for (int u = 0; u < 4; ++u)
#pragma unroll
        for (int v = 0; v < 4; ++v) acc[u][v] = 0.f;
    for (int k = 0; k < 64; ++k) {
        float a0 = As[(tr + 0) * 64 + k], a1 = As[(tr + 1) * 64 + k];
        float a2 = As[(tr + 2) * 64 + k], a3 = As[(tr + 3) * 64 + k];
        float b0 = Bs[k * 64 + tc + 0], b1 = Bs[k * 64 + tc + 1];
        float b2 = Bs[k * 64 + tc + 2], b3 = Bs[k * 64 + tc + 3];
        acc[0][0] = fmaf(a0, b0, acc[0][0]); acc[0][1] = fmaf(a0, b1, acc[0][1]);
        acc[0][2] = fmaf(a0, b2, acc[0][2]); acc[0][3] = fmaf(a0, b3, acc[0][3]);
        acc[1][0] = fmaf(a1, b0, acc[1][0]); acc[1][1] = fmaf(a1, b1, acc[1][1]);
        acc[1][2] = fmaf(a1, b2, acc[1][2]); acc[1][3] = fmaf(a1, b3, acc[1][3]);
        acc[2][0] = fmaf(a2, b0, acc[2][0]); acc[2][1] = fmaf(a2, b1, acc[2][1]);
        acc[2][2] = fmaf(a2, b2, acc[2][2]); acc[2][3] = fmaf(a2, b3, acc[2][3]);
        acc[3][0] = fmaf(a3, b0, acc[3][0]); acc[3][1] = fmaf(a3, b1, acc[3][1]);
        acc[3][2] = fmaf(a3, b2, acc[3][2]); acc[3][3] = fmaf(a3, b3, acc[3][3]);
    }
#pragma unroll
    for (int u = 0; u < 4; ++u)
#pragma unroll
        for (int v = 0; v < 4; ++v) Dm[(tr + u) * 64 + tc + v] = acc[u][v];
}

// ============ L[l,d,k,j] = sum_i B[l,i,d] Q_k[i,j];  R[l,d,r,i] = sum_j P_r[i,j] C[l,d,j] ============
__global__ __launch_bounds__(256) void k_lr(const float* __restrict__ P, const float* __restrict__ Q,
                                            const float* __restrict__ s4B, const float* __restrict__ s4C,
                                            float* __restrict__ L, float* __restrict__ R) {
    __shared__ float Ms[4096];
    int l = blockIdx.x >> 6, rem = blockIdx.x & 63, which = rem >> 5, idx = rem & 31;
    const float* M = which ? (P + (size_t)(l * 33 + idx) * 4096)
                           : (Q + (size_t)(l * 32 + idx) * 4096);
    for (int i = threadIdx.x; i < 4096; i += 256) Ms[i] = M[i];
    __syncthreads();
    int d = threadIdx.x;
    if (which == 0) {
        float* dst = L + (((size_t)(l * DD + d) * 32 + idx) * 64);
        for (int jc = 0; jc < 8; ++jc) {
            float acc[8];
#pragma unroll
            for (int u = 0; u < 8; ++u) acc[u] = 0.f;
            for (int i = 0; i < 64; ++i) {
                float bv = s4B[(l * NN + i) * DD + d];
#pragma unroll
                for (int u = 0; u < 8; ++u)
                    acc[u] = fmaf(bv, Ms[i * 64 + jc * 8 + u], acc[u]);
            }
#pragma unroll
            for (int u = 0; u < 8; ++u) dst[jc * 8 + u] = acc[u];
        }
    } else {
        float* dst = R + (((size_t)(l * DD + d) * 32 + idx) * 64);
        const float* Cp = s4C + (size_t)(l * DD + d) * NN;
        for (int ic = 0; ic < 8; ++ic) {
            float acc[8];
#pragma unroll
            for (int u = 0; u < 8; ++u) acc[u] = 0.f;
            for (int j = 0; j < 64; ++j) {
                float cv = Cp[j];
#pragma unroll
                for (int u = 0; u < 8; ++u)
                    acc[u] = fmaf(Ms[(ic * 8 + u) * 64 + j], cv, acc[u]);
            }
#pragma unroll
            for (int u = 0; u < 8; ++u) dst[ic * 8 + u] = acc[u];
        }
    }
}

// ============ k[l,d,t] = decay(t) * dot(L[l,d,t>>5,:], R[l,d,t&31,:]) ============
__global__ __launch_bounds__(256) void k_kker(const float* __restrict__ L, const float* __restrict__ R,
                                              float* __restrict__ kk) {
    __shared__ float Ls[32 * 65], Rs[32 * 65];
    int l = blockIdx.x >> 8, d = blockIdx.x & 255;
    const float* Lp = L + ((size_t)(l * DD + d) * 32) * 64;
    const float* Rp = R + ((size_t)(l * DD + d) * 32) * 64;
    for (int i = threadIdx.x; i < 2048; i += 256) {
        int row = i >> 6, col = i & 63;
        Ls[row * 65 + col] = Lp[i];
        Rs[row * 65 + col] = Rp[i];
    }
    __syncthreads();
    for (int t = threadIdx.x; t < TT; t += 256) {
        int kq = t >> 5, r = t & 31;
        const float* lr = &Ls[kq * 65];
        const float* rr = &Rs[r * 65];
        float a = 0.f;
#pragma unroll 8
        for (int m = 0; m < 64; ++m) a = fmaf(lr[m], rr[m], a);
        kk[(size_t)(l * DD + d) * TT + t] = a * expf(-0.01f * (float)t);
    }
}

// ============ embed: h[b,d,t] = sum_c w_in[d,c] x[b,c,t] + b_in[d] ============
__global__ __launch_bounds__(256) void k_embed(const float* __restrict__ x, const float* __restrict__ w_in,
                                               const float* __restrict__ b_in, float* __restrict__ h) {
    __shared__ float xt[CC][64];
    int b = blockIdx.y, t0 = blockIdx.x * 64;
    for (int i = threadIdx.x; i < CC * 64; i += 256) {
        int c = i >> 6, tl = i & 63;
        int t = t0 + tl;
        xt[c][tl] = (t < TT) ? x[(size_t)(b * CC + c) * TT + t] : 0.f;
    }
    __syncthreads();
    int w = threadIdx.x >> 6, lane = threadIdx.x & 63;
    int t = t0 + lane;
    for (int d0 = w * 64; d0 < w * 64 + 64; d0 += 4) {
        float a0 = b_in[d0], a1 = b_in[d0 + 1], a2 = b_in[d0 + 2], a3 = b_in[d0 + 3];
        for (int c = 0; c < CC; ++c) {
            float xv = xt[c][lane];
            a0 = fmaf(w_in[(d0 + 0) * CC + c], xv, a0);
            a1 = fmaf(w_in[(d0 + 1) * CC + c], xv, a1);
            a2 = fmaf(w_in[(d0 + 2) * CC + c], xv, a2);
            a3 = fmaf(w_in[(d0 + 3) * CC + c], xv, a3);
        }
        if (t < TT) {
            h[(size_t)(b * DD + d0 + 0) * TT + t] = a0;
            h[(size_t)(b * DD + d0 + 1) * TT + t] = a1;
            h[(size_t)(b * DD + d0 + 2) * TT + t] = a2;
            h[(size_t)(b * DD + d0 + 3) * TT + t] = a3;
        }
    }
}

// ============ LayerNorm over d (in-place), optional +pos-encoding, fused invn ============
__global__ __launch_bounds__(256) void k_ln(const float* __restrict__ in, const float* __restrict__ g,
                                            const float* __restrict__ bia, float* __restrict__ out,
                                            float* __restrict__ invn, int add_pe) {
    int b = blockIdx.y, t0 = blockIdx.x * 64;
    int w = threadIdx.x >> 6, lane = threadIdx.x & 63;
    int t = t0 + lane;
    __shared__ float ps[4][64], ps2[4][64];
    float s = 0.f, s2 = 0.f;
    if (t < TT)
        for (int d = w; d < DD; d += 4) {
            float v = in[(size_t)(b * DD + d) * TT + t];
            s += v; s2 = fmaf(v, v, s2);
        }
    ps[w][lane] = s; ps2[w][lane] = s2;
    __syncthreads();
    float mean = (ps[0][lane] + ps[1][lane] + ps[2][lane] + ps[3][lane]) * (1.f / 256.f);
    float ex2  = (ps2[0][lane] + ps2[1][lane] + ps2[2][lane] + ps2[3][lane]) * (1.f / 256.f);
    float rstd = 1.f / sqrtf(ex2 - mean * mean + 1e-5f);
    float sq = 0.f;
    if (t < TT) {
        float ft = (float)t;
        for (int d = w; d < DD; d += 4) {
            size_t ix = (size_t)(b * DD + d) * TT + t;
            float v = in[ix];
            float o = (v - mean) * rstd * g[d] + bia[d];
            if (add_pe) {
                float freq = expf((float)(d & ~1) * (-9.210340371976184f / 256.f));
                float ang = ft * freq;
                o += (d & 1) ? cosf(ang) : sinf(ang);
            }
            out[ix] = o;
            sq = fmaf(o, o, sq);
        }
    }
    __syncthreads();
    ps[w][lane] = sq;
    __syncthreads();
    if (w == 0 && t < TT) {
        float tot = ps[0][lane] + ps[1][lane] + ps[2][lane] + ps[3][lane];
        invn[b * TT + t] = 1.f / (sqrtf(tot) + 1e-8f);
    }
}

__device__ __forceinline__ float gelu_exact(float y) {
    return 0.5f * y * (1.f + erff(y * 0.7071067811865476f));
}

// ============ fused causal conv + gate + gelu + residual, in-place on h ============
__global__ __launch_bounds__(256) void k_conv(float* __restrict__ h, const float* __restrict__ kk,
                                              const float* __restrict__ invn, const float* __restrict__ s4D,
                                              int layer) {
    __shared__ __align__(16) float xs[2048];
    __shared__ __align__(16) float ks[1024];
    __shared__ float hr[1024];
    int d = blockIdx.x, b = blockIdx.y;
    int tid = threadIdx.x;
    float* hrow = h + (size_t)(b * DD + d) * TT;
    const float* krow = kk + (size_t)(layer * DD + d) * TT;
    for (int m = tid; m < 1024; m += 256) xs[m] = 0.f;
    for (int m = tid; m < TT; m += 256) {
        float v = hrow[m];
        hr[m] = v;
        xs[1024 + m] = v * invn[b * TT + m];
        ks[m] = krow[m];
    }
    __syncthreads();
    if (tid < 250) {
        const float4* xs4 = (const float4*)xs;
        const float4* ks4 = (const float4*)ks;
        int t0 = tid * 4;
        int base = (1024 + t0) >> 2;
        float acc0 = 0.f, acc1 = 0.f, acc2 = 0.f, acc3 = 0.f;
        float4 hi = xs4[base];
        int tmaxw = (tid | 63); if (tmaxw > 249) tmaxw = 249;
        int iters = tmaxw + 1;   // wave-uniform
        for (int s4 = 0; s4 < iters; ++s4) {
            float4 lo = xs4[base - s4 - 1];
            float4 k4 = ks4[s4];
            acc0 = fmaf(k4.x, hi.x, acc0); acc0 = fmaf(k4.y, lo.w, acc0);
            acc0 = fmaf(k4.z, lo.z, acc0); acc0 = fmaf(k4.w, lo.y, acc0);
            acc1 = fmaf(k4.x, hi.y, acc1); acc1 = fmaf(k4.y, hi.x, acc1);
            acc1 = fmaf(k4.z, lo.w, acc1); acc1 = fmaf(k4.w, lo.z, acc1);
            acc2 = fmaf(k4.x, hi.z, acc2); acc2 = fmaf(k4.y, hi.y, acc2);
            acc2 = fmaf(k4.z, hi.x, acc2); acc2 = fmaf(k4.w, lo.w, acc2);
            acc3 = fmaf(k4.x, hi.w, acc3); acc3 = fmaf(k4.y, hi.z, acc3);
            acc3 = fmaf(k4.z, hi.y, acc3); acc3 = fmaf(k4.w, hi.x, acc3);
            hi = lo;
        }
        float gate = 1.f / (1.f + expf(-s4D[layer * DD + d]));
        float o0 = gelu_exact(acc0 + xs[1024 + t0 + 0] * gate) + 1.1f * hr[t0 + 0];
        float o1 = gelu_exact(acc1 + xs[1024 + t0 + 1] * gate) + 1.1f * hr[t0 + 1];
        float o2 = gelu_exact(acc2 + xs[1024 + t0 + 2] * gate) + 1.1f * hr[t0 + 2];
        float o3 = gelu_exact(acc3 + xs[1024 + t0 + 3] * gate) + 1.1f * hr[t0 + 3];
        float4 o4; o4.x = o0; o4.y = o1; o4.z = o2; o4.w = o3;
        ((float4*)hrow)[tid] = o4;
    }
}

// ============ MHA pooling ============
__global__ __launch_bounds__(256) void k_qprep(const float* __restrict__ cls, const float* __restrict__ inw,
                                               const float* __restrict__ inb, float* __restrict__ qk,
                                               float* __restrict__ qb) {
    __shared__ float Qv[256];
    int j = threadIdx.x;
    float a = inb[j];
    for (int i = 0; i < 256; ++i) a = fmaf(inw[j * DD + i], cls[i], a);
    Qv[j] = a;
    __syncthreads();
    const float scale = 0.17677669529663687f; // 1/sqrt(32)
    for (int idx = threadIdx.x; idx < 8 * 256; idx += 256) {
        int hh = idx >> 8, i = idx & 255;
        float s = 0.f;
        for (int jj = 0; jj < 32; ++jj)
            s = fmaf(Qv[hh * 32 + jj], inw[(DD + hh * 32 + jj) * DD + i], s);
        qk[idx] = s * scale;
    }
    if (threadIdx.x < 8) {
        int hh = threadIdx.x;
        float s = 0.f;
        for (int jj = 0; jj < 32; ++jj)
            s = fmaf(Qv[hh * 32 + jj], inb[DD + hh * 32 + jj], s);
        qb[hh] = s * scale;
    }
}

__global__ __launch_bounds__(256) void k_scores(const float* __restrict__ h, const float* __restrict__ cls,
                                                const float* __restrict__ qkw, const float* __restrict__ qbw,
                                                float* __restrict__ sc) {
    __shared__ float qks[8 * 256];
    int b = blockIdx.y;
    int s = blockIdx.x * 256 + threadIdx.x;
    for (int i = threadIdx.x; i < 2048; i += 256) qks[i] = qkw[i];
    __syncthreads();
    if (s >= TT + 1) return;
    float acc[8];
#pragma unroll
    for (int hh = 0; hh < 8; ++hh) acc[hh] = qbw[hh];
    if (s == 0) {
        for (int i = 0; i < 256; ++i) {
            float v = cls[i];
#pragma unroll
            for (int hh = 0; hh < 8; ++hh) acc[hh] = fmaf(qks[hh * 256 + i], v, acc[hh]);
        }
    } else {
        const float* hb = h + (size_t)b * DD * TT + (s - 1);
        for (int i = 0; i < 256; ++i) {
            float v = hb[(size_t)i * TT];
#pragma unroll
            for (int hh = 0; hh < 8; ++hh) acc[hh] = fmaf(qks[hh * 256 + i], v, acc[hh]);
        }
    }
#pragma unroll
    for (int hh = 0; hh < 8; ++hh) sc[(size_t)(b * 8 + hh) * 1024 + s] = acc[hh];
}

__global__ __launch_bounds__(256) void k_softmax(const float* __restrict__ sc, float* __restrict__ att) {
    int row = blockIdx.x;
    const float* p = sc + (size_t)row * 1024;
    float* o = att + (size_t)row * 1024;
    __shared__ float red[256];
    float m = -3.4e38f;
    for (int s = threadIdx.x; s < TT + 1; s += 256) m = fmaxf(m, p[s]);
    red[threadIdx.x] = m; __syncthreads();
    for (int st = 128; st; st >>= 1) {
        if (threadIdx.x < st) red[threadIdx.x] = fmaxf(red[threadIdx.x], red[threadIdx.x + st]);
        __syncthreads();
    }
    m = red[0]; __syncthreads();
    float sum = 0.f;
    for (int s = threadIdx.x; s < TT + 1; s += 256) {
        float e = expf(p[s] - m);
        o[s] = e; sum += e;
    }
    red[threadIdx.x] = sum; __syncthreads();
    for (int st = 128; st; st >>= 1) {
        if (threadIdx.x < st) red[threadIdx.x] += red[threadIdx.x + st];
        __syncthreads();
    }
    float inv = 1.f / red[0];
    for (int s = threadIdx.x; s < TT + 1; s += 256) o[s] *= inv;
}

__global__ __launch_bounds__(256) void k_ctx(const float* __restrict__ h, const float* __restrict__ cls,
                                             const float* __restrict__ att, float* __restrict__ ctx) {
    __shared__ float as[8][1024];
    int b = blockIdx.y, i0 = blockIdx.x * 32;
    for (int idx = threadIdx.x; idx < 8 * 1024; idx += 256) {
        int hh = idx >> 10, s = idx & 1023;
        as[hh][s] = (s < TT + 1) ? att[(size_t)(b * 8 + hh) * 1024 + s] : 0.f;
    }
    __syncthreads();
    int w = threadIdx.x >> 6, lane = threadIdx.x & 63;
    for (int ii = 0; ii < 8; ++ii) {
        int i = i0 + w * 8 + ii;
        const float* hb = h + (size_t)(b * DD + i) * TT;
        float acc[8];
#pragma unroll
        for (int hh = 0; hh < 8; ++hh) acc[hh] = 0.f;
        for (int t = lane; t < TT; t += 64) {
            float v = hb[t];
#pragma unroll
            for (int hh = 0; hh < 8; ++hh) acc[hh] = fmaf(as[hh][t + 1], v, acc[hh]);
        }
#pragma unroll
        for (int off = 32; off; off >>= 1)
#pragma unroll
            for (int hh = 0; hh < 8; ++hh) acc[hh] += __shfl_down(acc[hh], off);
        if (lane == 0) {
#pragma unroll
            for (int hh = 0; hh < 8; ++hh)
                ctx[(size_t)(b * 8 + hh) * DD + i] = acc[hh] + as[hh][0] * cls[i];
        }
    }
}

__global__ __launch_bounds__(256) void k_head(const float* __restrict__ ctx, const float* __restrict__ inw,
                                              const float* __restrict__ inb, const float* __restrict__ outw,
                                              const float* __restrict__ outb, const float* __restrict__ w1,
                                              const float* __restrict__ b1, const float* __restrict__ w2,
                                              const float* __restrict__ b2, float* __restrict__ out) {
    int b = blockIdx.x;
    __shared__ float cs[2048], ao[256], po[256], hid[128];
    for (int i = threadIdx.x; i < 2048; i += 256) cs[i] = ctx[(size_t)b * 2048 + i];
    __syncthreads();
    int j = threadIdx.x;
    {
        int hh = j >> 5;
        float a = inb[2 * DD + j];
        const float* wv = inw + (size_t)(2 * DD + j) * DD;
        for (int i = 0; i < 256; ++i) a = fmaf(wv[i], cs[hh * 256 + i], a);
        ao[j] = a;
    }
    __syncthreads();
    {
        float a = outb[j];
        for (int i = 0; i < 256; ++i) a = fmaf(outw[j * DD + i], ao[i], a);
        po[j] = a;
    }
    __syncthreads();
    if (j < 128) {
        float a = b1[j];
        for (int i = 0; i < 256; ++i) a = fmaf(w1[j * 256 + i], po[i], a);
        hid[j] = fmaxf(a, 0.f);
    }
    __syncthreads();
    if (j == 0) {
        float a = b2[0];
        for (int i = 0; i < 128; ++i) a = fmaf(w2[i], hid[i], a);
        out[b] = a;
    }
}

extern "C" void kernel_launch(void* const* d_in, const int* in_sizes, int n_in,
                              void* d_out, int out_size, void* d_ws, size_t ws_size,
                              hipStream_t stream) {
    (void)in_sizes; (void)n_in; (void)out_size; (void)ws_size;
    const float* x        = (const float*)d_in[0];
    const float* w_in     = (const float*)d_in[1];
    const float* b_in     = (const float*)d_in[2];
    const float* ln_in_g  = (const float*)d_in[3];
    const float* ln_in_b  = (const float*)d_in[4];
    const float* s4B      = (const float*)d_in[5];
    const float* s4C      = (const float*)d_in[6];
    const float* s4logdt  = (const float*)d_in[7];
    const float* s4D      = (const float*)d_in[8];
    const float* ln_g     = (const float*)d_in[9];
    const float* ln_b     = (const float*)d_in[10];
    const float* cls      = (const float*)d_in[11];
    const float* mha_in_w = (const float*)d_in[12];
    const float* mha_in_b = (const float*)d_in[13];
    const float* mha_out_w= (const float*)d_in[14];
    const float* mha_out_b= (const float*)d_in[15];
    const float* head_w1  = (const float*)d_in[16];
    const float* head_b1  = (const float*)d_in[17];
    const float* head_w2  = (const float*)d_in[18];
    const float* head_b2  = (const float*)d_in[19];

    float* ws   = (float*)d_ws;
    float* h    = ws + OFF_H;
    float* kker = ws + OFF_K;
    float* Ad   = ws + OFF_AD;
    float* invn = ws + OFF_INV;
    // overlay power-tree buffers in (currently dead) h region
    float* P  = h;
    float* Q  = h + 540672;
    float* Lb = h + 1064960;
    float* Rb = h + 3162112;
    // MHA scratch
    float* qkb  = ws + OFF_MHA;
    float* qbb  = qkb + 2048;
    float* scb  = qbb + 16;
    float* attb = scb + 262144;
    float* ctxb = attb + 262144;

    k_build_ad<<<dim3(NLY), dim3(256), 0, stream>>>(s4logdt, Ad);
    k_pq_init<<<dim3(NLY), dim3(256), 0, stream>>>(Ad, P);
    for (int m = 1; m <= 5; ++m) {
        int half = 1 << (m - 1);
        k_mm64<<<dim3(half, NLY), dim3(256), 0, stream>>>(P, half, 33);
    }
    k_q_init<<<dim3(NLY), dim3(256), 0, stream>>>(P, Q);
    for (int m = 1; m <= 5; ++m) {
        int half = 1 << (m - 1);
        int cnt = (m == 5) ? 15 : half;
        k_mm64<<<dim3(cnt, NLY), dim3(256), 0, stream>>>(Q, half, 32);
    }
    k_lr<<<dim3(NLY * 64), dim3(256), 0, stream>>>(P, Q, s4B, s4C, Lb, Rb);
    k_kker<<<dim3(NLY * 256), dim3(256), 0, stream>>>(Lb, Rb, kker);

    k_embed<<<dim3(16, BB), dim3(256), 0, stream>>>(x, w_in, b_in, h);
    k_ln<<<dim3(16, BB), dim3(256), 0, stream>>>(h, ln_in_g, ln_in_b, h, invn, 1);

    for (int l = 0; l < NLY; ++l) {
        k_conv<<<dim3(DD, BB), dim3(256), 0, stream>>>(h, kker, invn, s4D, l);
        k_ln<<<dim3(16, BB), dim3(256), 0, stream>>>(h, ln_g + l * DD, ln_b + l * DD, h, invn, 0);
    }

    k_qprep<<<dim3(1), dim3(256), 0, stream>>>(cls, mha_in_w, mha_in_b, qkb, qbb);
    k_scores<<<dim3(4, BB), dim3(256), 0, stream>>>(h, cls, qkb, qbb, scb);
    k_softmax<<<dim3(256), dim3(256), 0, stream>>>(scb, attb);
    k_ctx<<<dim3(8, BB), dim3(256), 0, stream>>>(h, cls, attb, ctxb);
    k_head<<<dim3(BB), dim3(256), 0, stream>>>(ctxb, mha_in_w, mha_in_b, mha_out_w, mha_out_b,
                                               head_w1, head_b1, head_w2, head_b2, (float*)d_out);
}

// Round 3
// 1188.830 us; speedup vs baseline: 1.5475x; 1.3060x over previous
//
#include <hip/hip_runtime.h>

#define BB 32
#define CC 129
#define TT 1000
#define DD 256
#define NN 64
#define NLY 4

// ---------------- workspace layout (floats) ----------------
#define OFF_H    0
#define OFF_K    8192000
#define OFF_AD   9216000
#define OFF_INV  9232384
#define OFF_MHA  9264384

typedef __attribute__((ext_vector_type(8))) short bf16x8;
typedef __attribute__((ext_vector_type(4))) float f32x4;

__device__ __forceinline__ unsigned short f2bf(float x) {
    unsigned int u = __float_as_uint(x);
    unsigned int r = (u + 0x7FFF + ((u >> 16) & 1)) >> 16;
    return (unsigned short)r;
}
__device__ __forceinline__ float bf2f(unsigned short b) {
    return __uint_as_float(((unsigned int)b) << 16);
}

// ============ Ad = (I - dtA/2)^-1 (I + dtA/2), Gauss-Jordan w/ partial pivot ============
#define ST 131
__global__ __launch_bounds__(256) void k_build_ad(const float* __restrict__ logdt,
                                                  float* __restrict__ Ad) {
    __shared__ float M[64 * ST];
    __shared__ int piv;
    int l = blockIdx.x;
    int tid = threadIdx.x;
    int q = tid >> 6, r = tid & 63;
    float dt = expf(logdt[l * DD]);
    dt = fminf(fmaxf(dt, 1e-4f), 0.1f);
    float hh = dt * 0.5f;
    float Pr = sqrtf(1.f + 2.f * (float)r);
    for (int j = q; j < 130; j += 4) {
        int jj = (j < 64) ? j : (j - 64);
        float a;
        if (r == jj) a = -((float)r + 0.5f);
        else { float m = Pr * sqrtf(1.f + 2.f * (float)jj); a = (r > jj) ? -m : m; }
        float ident = (r == jj) ? 1.f : 0.f;
        M[r * ST + j] = (j < 64) ? (ident - hh * a) : (ident + hh * a);
    }
    __syncthreads();
    for (int c = 0; c < 64; ++c) {
        if (tid < 64) {
            float bv = (r >= c) ? fabsf(M[r * ST + c]) : -1.f;
            int bi = r;
            for (int off = 32; off; off >>= 1) {
                float ov = __shfl_xor(bv, off);
                int oi = __shfl_xor(bi, off);
                if (ov > bv) { bv = ov; bi = oi; }
            }
            if (tid == 0) piv = bi;
        }
        __syncthreads();
        int p = piv;
        if (tid >= c && tid < 130) {
            float pv = M[p * ST + c];
            float inv = 1.f / pv;
            if (p != c) {
                float a = M[c * ST + tid], b2 = M[p * ST + tid];
                M[p * ST + tid] = a;
                M[c * ST + tid] = (tid > c) ? b2 * inv : b2;
            } else if (tid > c) {
                M[c * ST + tid] *= inv;
            }
        }
        __syncthreads();
        if (r != c) {
            float f = M[r * ST + c];
            int base = c + 1;
            int j0 = base + (((q - base) % 4) + 4) % 4;
            for (int j = j0; j < 130; j += 4)
                M[r * ST + j] = fmaf(-f, M[c * ST + j], M[r * ST + j]);
        }
        __syncthreads();
    }
    for (int i = tid; i < 4096; i += 256) {
        int rr = i >> 6, j = i & 63;
        Ad[(l * 64 + rr) * 64 + j] = M[rr * ST + 64 + j];
    }
}

// ============ power tree ============
__global__ __launch_bounds__(256) void k_pq_init(const float* __restrict__ Ad, float* __restrict__ P) {
    int l = blockIdx.x;
    for (int i = threadIdx.x; i < 4096; i += 256) {
        int r = i >> 6, c = i & 63;
        P[(l * 33 + 0) * 4096 + i] = (r == c) ? 1.f : 0.f;
        P[(l * 33 + 1) * 4096 + i] = Ad[l * 4096 + i];
    }
}

__global__ __launch_bounds__(256) void k_q_init(const float* __restrict__ P, float* __restrict__ Q) {
    int l = blockIdx.x;
    for (int i = threadIdx.x; i < 4096; i += 256) {
        int r = i >> 6, c = i & 63;
        Q[(l * 32 + 0) * 4096 + i] = (r == c) ? 1.f : 0.f;
        Q[(l * 32 + 1) * 4096 + i] = P[(l * 33 + 32) * 4096 + i];
    }
}

__global__ __launch_bounds__(256) void k_mm64(float* __restrict__ base, int half, int smats) {
    __shared__ float As[4096], Bs[4096];
    int l = blockIdx.y;
    int j = half + 1 + blockIdx.x;
    const float* Am = base + (size_t)(l * smats + half) * 4096;
    const float* Bm = base + (size_t)(l * smats + (j - half)) * 4096;
    float* Dm = base + (size_t)(l * smats + j) * 4096;
    for (int i = threadIdx.x; i < 4096; i += 256) { As[i] = Am[i]; Bs[i] = Bm[i]; }
    __syncthreads();
    int tr = (threadIdx.x >> 4) << 2;
    int tc = (threadIdx.x & 15) << 2;
    float acc[4][4];
#pragma unroll
    for (int u = 0; u < 4; ++u)
#pragma unroll
        for (int v = 0; v < 4; ++v) acc[u][v] = 0.f;
    for (int k = 0; k < 64; ++k) {
        float a0 = As[(tr + 0) * 64 + k], a1 = As[(tr + 1) * 64 + k];
        float a2 = As[(tr + 2) * 64 + k], a3 = As[(tr + 3) * 64 + k];
        float b0 = Bs[k * 64 + tc + 0], b1 = Bs[k * 64 + tc + 1];
        float b2 = Bs[k * 64 + tc + 2], b3 = Bs[k * 64 + tc + 3];
        acc[0][0] = fmaf(a0, b0, acc[0][0]); acc[0][1] = fmaf(a0, b1, acc[0][1]);
        acc[0][2] = fmaf(a0, b2, acc[0][2]); acc[0][3] = fmaf(a0, b3, acc[0][3]);
        acc[1][0] = fmaf(a1, b0, acc[1][0]); acc[1][1] = fmaf(a1, b1, acc[1][1]);
        acc[1][2] = fmaf(a1, b2, acc[1][2]); acc[1][3] = fmaf(a1, b3, acc[1][3]);
        acc[2][0] = fmaf(a2, b0, acc[2][0]); acc[2][1] = fmaf(a2, b1, acc[2][1]);
        acc[2][2] = fmaf(a2, b2, acc[2][2]); acc[2][3] = fmaf(a2, b3, acc[2][3]);
        acc[3][0] = fmaf(a3, b0, acc[3][0]); acc[3][1] = fmaf(a3, b1, acc[3][1]);
        acc[3][2] = fmaf(a3, b2, acc[3][2]); acc[3][3] = fmaf(a3, b3, acc[3][3]);
    }
#pragma unroll
    for (int u = 0; u < 4; ++u)
#pragma unroll
        for (int v = 0; v < 4; ++v) Dm[(tr + u) * 64 + tc + v] = acc[u][v];
}

// ============ L / R ============
__global__ __launch_bounds__(256) void k_lr(const float* __restrict__ P, const float* __restrict__ Q,
                                            const float* __restrict__ s4B, const float* __restrict__ s4C,
                                            float* __restrict__ L, float* __restrict__ R) {
    __shared__ float Ms[4096];
    int l = blockIdx.x >> 6, rem = blockIdx.x & 63, which = rem >> 5, idx = rem & 31;
    const float* M = which ? (P + (size_t)(l * 33 + idx) * 4096)
                           : (Q + (size_t)(l * 32 + idx) * 4096);
    for (int i = threadIdx.x; i < 4096; i += 256) Ms[i] = M[i];
    __syncthreads();
    int d = threadIdx.x;
    if (which == 0) {
        float* dst = L + (((size_t)(l * DD + d) * 32 + idx) * 64);
        for (int jc = 0; jc < 8; ++jc) {
            float acc[8];
#pragma unroll
            for (int u = 0; u < 8; ++u) acc[u] = 0.f;
            for (int i = 0; i < 64; ++i) {
                float bv = s4B[(l * NN + i) * DD + d];
#pragma unroll
                for (int u = 0; u < 8; ++u)
                    acc[u] = fmaf(bv, Ms[i * 64 + jc * 8 + u], acc[u]);
            }
#pragma unroll
            for (int u = 0; u < 8; ++u) dst[jc * 8 + u] = acc[u];
        }
    } else {
        float* dst = R + (((size_t)(l * DD + d) * 32 + idx) * 64);
        const float* Cp = s4C + (size_t)(l * DD + d) * NN;
        for (int ic = 0; ic < 8; ++ic) {
            float acc[8];
#pragma unroll
            for (int u = 0; u < 8; ++u) acc[u] = 0.f;
            for (int j = 0; j < 64; ++j) {
                float cv = Cp[j];
#pragma unroll
                for (int u = 0; u < 8; ++u)
                    acc[u] = fmaf(Ms[(ic * 8 + u) * 64 + j], cv, acc[u]);
            }
#pragma unroll
            for (int u = 0; u < 8; ++u) dst[ic * 8 + u] = acc[u];
        }
    }
}

// ============ kernel assembly ============
__global__ __launch_bounds__(256) void k_kker(const float* __restrict__ L, const float* __restrict__ R,
                                              float* __restrict__ kk) {
    __shared__ float Ls[32 * 65], Rs[32 * 65];
    int l = blockIdx.x >> 8, d = blockIdx.x & 255;
    const float* Lp = L + ((size_t)(l * DD + d) * 32) * 64;
    const float* Rp = R + ((size_t)(l * DD + d) * 32) * 64;
    for (int i = threadIdx.x; i < 2048; i += 256) {
        int row = i >> 6, col = i & 63;
        Ls[row * 65 + col] = Lp[i];
        Rs[row * 65 + col] = Rp[i];
    }
    __syncthreads();
    for (int t = threadIdx.x; t < TT; t += 256) {
        int kq = t >> 5, r = t & 31;
        const float* lr = &Ls[kq * 65];
        const float* rr = &Rs[r * 65];
        float a = 0.f;
#pragma unroll 8
        for (int m = 0; m < 64; ++m) a = fmaf(lr[m], rr[m], a);
        kk[(size_t)(l * DD + d) * TT + t] = a * expf(-0.01f * (float)t);
    }
}

// ============ embed: h[b,d,t] = sum_c w_in[d,c] x[b,c,t] + b_in[d] ============
// w_in index made wave-uniform (readfirstlane) -> scalar s_load broadcast path
__global__ __launch_bounds__(256) void k_embed(const float* __restrict__ x, const float* __restrict__ w_in,
                                               const float* __restrict__ b_in, float* __restrict__ h) {
    __shared__ float xt[CC][64];
    int b = blockIdx.y, t0 = blockIdx.x * 64;
    for (int i = threadIdx.x; i < CC * 64; i += 256) {
        int c = i >> 6, tl = i & 63;
        int t = t0 + tl;
        xt[c][tl] = (t < TT) ? x[(size_t)(b * CC + c) * TT + t] : 0.f;
    }
    __syncthreads();
    int w = threadIdx.x >> 6, lane = threadIdx.x & 63;
    int t = t0 + lane;
    int dbase = __builtin_amdgcn_readfirstlane(w * 64);
    for (int du = 0; du < 64; du += 4) {
        int d0 = dbase + du;
        float a0 = b_in[d0], a1 = b_in[d0 + 1], a2 = b_in[d0 + 2], a3 = b_in[d0 + 3];
        const float* w0 = w_in + (size_t)(d0 + 0) * CC;
        const float* w1 = w_in + (size_t)(d0 + 1) * CC;
        const float* w2 = w_in + (size_t)(d0 + 2) * CC;
        const float* w3 = w_in + (size_t)(d0 + 3) * CC;
#pragma unroll 4
        for (int c = 0; c < CC; ++c) {
            float xv = xt[c][lane];
            a0 = fmaf(w0[c], xv, a0);
            a1 = fmaf(w1[c], xv, a1);
            a2 = fmaf(w2[c], xv, a2);
            a3 = fmaf(w3[c], xv, a3);
        }
        if (t < TT) {
            h[(size_t)(b * DD + d0 + 0) * TT + t] = a0;
            h[(size_t)(b * DD + d0 + 1) * TT + t] = a1;
            h[(size_t)(b * DD + d0 + 2) * TT + t] = a2;
            h[(size_t)(b * DD + d0 + 3) * TT + t] = a3;
        }
    }
}

// ============ LayerNorm over d (in-place), optional +pos-encoding, fused invn ============
__global__ __launch_bounds__(256) void k_ln(const float* __restrict__ in, const float* __restrict__ g,
                                            const float* __restrict__ bia, float* __restrict__ out,
                                            float* __restrict__ invn, int add_pe) {
    int b = blockIdx.y, t0 = blockIdx.x * 64;
    int w = threadIdx.x >> 6, lane = threadIdx.x & 63;
    int t = t0 + lane;
    __shared__ float ps[4][64], ps2[4][64];
    float s = 0.f, s2 = 0.f;
    if (t < TT)
        for (int d = w; d < DD; d += 4) {
            float v = in[(size_t)(b * DD + d) * TT + t];
            s += v; s2 = fmaf(v, v, s2);
        }
    ps[w][lane] = s; ps2[w][lane] = s2;
    __syncthreads();
    float mean = (ps[0][lane] + ps[1][lane] + ps[2][lane] + ps[3][lane]) * (1.f / 256.f);
    float ex2  = (ps2[0][lane] + ps2[1][lane] + ps2[2][lane] + ps2[3][lane]) * (1.f / 256.f);
    float rstd = 1.f / sqrtf(ex2 - mean * mean + 1e-5f);
    float sq = 0.f;
    if (t < TT) {
        float ft = (float)t;
        for (int d = w; d < DD; d += 4) {
            size_t ix = (size_t)(b * DD + d) * TT + t;
            float v = in[ix];
            float o = (v - mean) * rstd * g[d] + bia[d];
            if (add_pe) {
                float freq = expf((float)(d & ~1) * (-9.210340371976184f / 256.f));
                float ang = ft * freq;
                o += (d & 1) ? cosf(ang) : sinf(ang);
            }
            out[ix] = o;
            sq = fmaf(o, o, sq);
        }
    }
    __syncthreads();
    ps[w][lane] = sq;
    __syncthreads();
    if (w == 0 && t < TT) {
        float tot = ps[0][lane] + ps[1][lane] + ps[2][lane] + ps[3][lane];
        invn[b * TT + t] = 1.f / (sqrtf(tot) + 1e-8f);
    }
}

__device__ __forceinline__ float gelu_exact(float y) {
    return 0.5f * y * (1.f + erff(y * 0.7071067811865476f));
}

// ============ MFMA conv: C[b,t] = sum_u Xn[b][u] * k[(t0+t)-(u0+u)] ============
// Per block: one d, 16 batches. Xn staged as split-bf16 (hi/lo) in LDS.
// Toeplitz kernel operand staged as pair-packed dwords pk[m]=(k~[m] lo | k~[m-1] hi)
// so the lane-varying fragment assembles from 4 aligned ds_read_b32.
// Split product: ah*bh + ah*bl + al*bh -> ~2^-16 relative error per product.
#define XSTR 1032
__global__ __launch_bounds__(256) void k_conv_mfma(float* __restrict__ h, const float* __restrict__ kk,
                                                   const float* __restrict__ invn,
                                                   const float* __restrict__ s4D, int layer) {
    __shared__ unsigned short Xh[16 * XSTR], Xl[16 * XSTR];
    __shared__ unsigned int pkh[1040], pkl[1040];
    int d = blockIdx.x, b0 = blockIdx.y * 16;
    int tid = threadIdx.x;
    const float* krow = kk + (size_t)(layer * DD + d) * TT;
    // stage kernel pair-dwords: pk[mm] = (bf(k~[mm-32]) low | bf(k~[mm-33]) high)
    for (int mm = tid; mm < 1040; mm += 256) {
        int m = mm - 32;
        float klo = (m >= 0 && m < TT) ? krow[m] : 0.f;
        float kpr = (m >= 1 && m <= TT) ? krow[m - 1] : 0.f;
        unsigned short lh = f2bf(klo); unsigned short ll = f2bf(klo - bf2f(lh));
        unsigned short ph = f2bf(kpr); unsigned short pl = f2bf(kpr - bf2f(ph));
        pkh[mm] = (unsigned int)lh | ((unsigned int)ph << 16);
        pkl[mm] = (unsigned int)ll | ((unsigned int)pl << 16);
    }
    // stage Xn split-bf16
    for (int i = tid; i < 16 * 1024; i += 256) {
        int bb = i >> 10, t = i & 1023;
        float v = 0.f;
        if (t < TT)
            v = h[((size_t)(b0 + bb) * DD + d) * TT + t] * invn[(b0 + bb) * TT + t];
        unsigned short vh = f2bf(v);
        unsigned short vl = f2bf(v - bf2f(vh));
        Xh[bb * XSTR + t] = vh;
        Xl[bb * XSTR + t] = vl;
    }
    __syncthreads();
    float gate = 1.f / (1.f + expf(-s4D[layer * DD + d]));
    int wave = tid >> 6, lane = tid & 63;
    int tn = lane & 15, qq = lane >> 4;
    for (int j = wave; j < 63; j += 4) {
        int t0 = j * 16;
        f32x4 acc1 = {0.f, 0.f, 0.f, 0.f};
        f32x4 acc2 = {0.f, 0.f, 0.f, 0.f};
        f32x4 acc3 = {0.f, 0.f, 0.f, 0.f};
        for (int u0 = 0; u0 <= t0 + 15; u0 += 32) {
            // A-frag: lane is batch m = tn, k = 8*qq + j (16B-aligned b128)
            const bf16x8 ah = *(const bf16x8*)&Xh[tn * XSTR + u0 + 8 * qq];
            const bf16x8 al = *(const bf16x8*)&Xl[tn * XSTR + u0 + 8 * qq];
            // B-frag: B[k=8q+e][n=tn] = k~[(t0-u0) + tn - 8q - e]
            int S32 = t0 - u0 + tn - 8 * qq + 32;
            union { bf16x8 v; unsigned int u[4]; } bh, bl;
            bh.u[0] = pkh[S32];     bl.u[0] = pkl[S32];
            bh.u[1] = pkh[S32 - 2]; bl.u[1] = pkl[S32 - 2];
            bh.u[2] = pkh[S32 - 4]; bl.u[2] = pkl[S32 - 4];
            bh.u[3] = pkh[S32 - 6]; bl.u[3] = pkl[S32 - 6];
            acc1 = __builtin_amdgcn_mfma_f32_16x16x32_bf16(ah, bh.v, acc1, 0, 0, 0);
            acc2 = __builtin_amdgcn_mfma_f32_16x16x32_bf16(ah, bl.v, acc2, 0, 0, 0);
            acc3 = __builtin_amdgcn_mfma_f32_16x16x32_bf16(al, bh.v, acc3, 0, 0, 0);
        }
        // C/D layout: col = lane&15 = t-within-tile, row = qq*4 + reg = batch
        int t = t0 + tn;
        if (t < TT) {
#pragma unroll
            for (int r = 0; r < 4; ++r) {
                int brow = 4 * qq + r;
                size_t ix = ((size_t)(b0 + brow) * DD + d) * TT + t;
                float y = acc1[r] + acc2[r] + acc3[r];
                float xn = bf2f(Xh[brow * XSTR + t]) + bf2f(Xl[brow * XSTR + t]);
                float ho = h[ix];
                h[ix] = gelu_exact(y + xn * gate) + 1.1f * ho;
            }
        }
    }
}

// ============ MHA pooling ============
__global__ __launch_bounds__(256) void k_qprep(const float* __restrict__ cls, const float* __restrict__ inw,
                                               const float* __restrict__ inb, float* __restrict__ qk,
                                               float* __restrict__ qb) {
    __shared__ float Qv[256];
    int j = threadIdx.x;
    float a = inb[j];
    for (int i = 0; i < 256; ++i) a = fmaf(inw[j * DD + i], cls[i], a);
    Qv[j] = a;
    __syncthreads();
    const float scale = 0.17677669529663687f; // 1/sqrt(32)
    for (int idx = threadIdx.x; idx < 8 * 256; idx += 256) {
        int hh = idx >> 8, i = idx & 255;
        float s = 0.f;
        for (int jj = 0; jj < 32; ++jj)
            s = fmaf(Qv[hh * 32 + jj], inw[(DD + hh * 32 + jj) * DD + i], s);
        qk[idx] = s * scale;
    }
    if (threadIdx.x < 8) {
        int hh = threadIdx.x;
        float s = 0.f;
        for (int jj = 0; jj < 32; ++jj)
            s = fmaf(Qv[hh * 32 + jj], inb[DD + hh * 32 + jj], s);
        qb[hh] = s * scale;
    }
}

__global__ __launch_bounds__(256) void k_scores(const float* __restrict__ h, const float* __restrict__ cls,
                                                const float* __restrict__ qkw, const float* __restrict__ qbw,
                                                float* __restrict__ sc) {
    __shared__ float qks[8 * 256];
    int b = blockIdx.y;
    int s = blockIdx.x * 256 + threadIdx.x;
    for (int i = threadIdx.x; i < 2048; i += 256) qks[i] = qkw[i];
    __syncthreads();
    if (s >= TT + 1) return;
    float acc[8];
#pragma unroll
    for (int hh = 0; hh < 8; ++hh) acc[hh] = qbw[hh];
    if (s == 0) {
        for (int i = 0; i < 256; ++i) {
            float v = cls[i];
#pragma unroll
            for (int hh = 0; hh < 8; ++hh) acc[hh] = fmaf(qks[hh * 256 + i], v, acc[hh]);
        }
    } else {
        const float* hb = h + (size_t)b * DD * TT + (s - 1);
        for (int i = 0; i < 256; ++i) {
            float v = hb[(size_t)i * TT];
#pragma unroll
            for (int hh = 0; hh < 8; ++hh) acc[hh] = fmaf(qks[hh * 256 + i], v, acc[hh]);
        }
    }
#pragma unroll
    for (int hh = 0; hh < 8; ++hh) sc[(size_t)(b * 8 + hh) * 1024 + s] = acc[hh];
}

__global__ __launch_bounds__(256) void k_softmax(const float* __restrict__ sc, float* __restrict__ att) {
    int row = blockIdx.x;
    const float* p = sc + (size_t)row * 1024;
    float* o = att + (size_t)row * 1024;
    __shared__ float red[256];
    float m = -3.4e38f;
    for (int s = threadIdx.x; s < TT + 1; s += 256) m = fmaxf(m, p[s]);
    red[threadIdx.x] = m; __syncthreads();
    for (int st = 128; st; st >>= 1) {
        if (threadIdx.x < st) red[threadIdx.x] = fmaxf(red[threadIdx.x], red[threadIdx.x + st]);
        __syncthreads();
    }
    m = red[0]; __syncthreads();
    float sum = 0.f;
    for (int s = threadIdx.x; s < TT + 1; s += 256) {
        float e = expf(p[s] - m);
        o[s] = e; sum += e;
    }
    red[threadIdx.x] = sum; __syncthreads();
    for (int st = 128; st; st >>= 1) {
        if (threadIdx.x < st) red[threadIdx.x] += red[threadIdx.x + st];
        __syncthreads();
    }
    float inv = 1.f / red[0];
    for (int s = threadIdx.x; s < TT + 1; s += 256) o[s] *= inv;
}

__global__ __launch_bounds__(256) void k_ctx(const float* __restrict__ h, const float* __restrict__ cls,
                                             const float* __restrict__ att, float* __restrict__ ctx) {
    __shared__ float as[8][1024];
    int b = blockIdx.y, i0 = blockIdx.x * 32;
    for (int idx = threadIdx.x; idx < 8 * 1024; idx += 256) {
        int hh = idx >> 10, s = idx & 1023;
        as[hh][s] = (s < TT + 1) ? att[(size_t)(b * 8 + hh) * 1024 + s] : 0.f;
    }
    __syncthreads();
    int w = threadIdx.x >> 6, lane = threadIdx.x & 63;
    for (int ii = 0; ii < 8; ++ii) {
        int i = i0 + w * 8 + ii;
        const float* hb = h + (size_t)(b * DD + i) * TT;
        float acc[8];
#pragma unroll
        for (int hh = 0; hh < 8; ++hh) acc[hh] = 0.f;
        for (int t = lane; t < TT; t += 64) {
            float v = hb[t];
#pragma unroll
            for (int hh = 0; hh < 8; ++hh) acc[hh] = fmaf(as[hh][t + 1], v, acc[hh]);
        }
#pragma unroll
        for (int off = 32; off; off >>= 1)
#pragma unroll
            for (int hh = 0; hh < 8; ++hh) acc[hh] += __shfl_down(acc[hh], off);
        if (lane == 0) {
#pragma unroll
            for (int hh = 0; hh < 8; ++hh)
                ctx[(size_t)(b * 8 + hh) * DD + i] = acc[hh] + as[hh][0] * cls[i];
        }
    }
}

__global__ __launch_bounds__(256) void k_head(const float* __restrict__ ctx, const float* __restrict__ inw,
                                              const float* __restrict__ inb, const float* __restrict__ outw,
                                              const float* __restrict__ outb, const float* __restrict__ w1,
                                              const float* __restrict__ b1, const float* __restrict__ w2,
                                              const float* __restrict__ b2, float* __restrict__ out) {
    int b = blockIdx.x;
    __shared__ float cs[2048], ao[256], po[256], hid[128];
    for (int i = threadIdx.x; i < 2048; i += 256) cs[i] = ctx[(size_t)b * 2048 + i];
    __syncthreads();
    int j = threadIdx.x;
    {
        int hh = j >> 5;
        float a = inb[2 * DD + j];
        const float* wv = inw + (size_t)(2 * DD + j) * DD;
        for (int i = 0; i < 256; ++i) a = fmaf(wv[i], cs[hh * 256 + i], a);
        ao[j] = a;
    }
    __syncthreads();
    {
        float a = outb[j];
        for (int i = 0; i < 256; ++i) a = fmaf(outw[j * DD + i], ao[i], a);
        po[j] = a;
    }
    __syncthreads();
    if (j < 128) {
        float a = b1[j];
        for (int i = 0; i < 256; ++i) a = fmaf(w1[j * 256 + i], po[i], a);
        hid[j] = fmaxf(a, 0.f);
    }
    __syncthreads();
    if (j == 0) {
        float a = b2[0];
        for (int i = 0; i < 128; ++i) a = fmaf(w2[i], hid[i], a);
        out[b] = a;
    }
}

extern "C" void kernel_launch(void* const* d_in, const int* in_sizes, int n_in,
                              void* d_out, int out_size, void* d_ws, size_t ws_size,
                              hipStream_t stream) {
    (void)in_sizes; (void)n_in; (void)out_size; (void)ws_size;
    const float* x        = (const float*)d_in[0];
    const float* w_in     = (const float*)d_in[1];
    const float* b_in     = (const float*)d_in[2];
    const float* ln_in_g  = (const float*)d_in[3];
    const float* ln_in_b  = (const float*)d_in[4];
    const float* s4B      = (const float*)d_in[5];
    const float* s4C      = (const float*)d_in[6];
    const float* s4logdt  = (const float*)d_in[7];
    const float* s4D      = (const float*)d_in[8];
    const float* ln_g     = (const float*)d_in[9];
    const float* ln_b     = (const float*)d_in[10];
    const float* cls      = (const float*)d_in[11];
    const float* mha_in_w = (const float*)d_in[12];
    const float* mha_in_b = (const float*)d_in[13];
    const float* mha_out_w= (const float*)d_in[14];
    const float* mha_out_b= (const float*)d_in[15];
    const float* head_w1  = (const float*)d_in[16];
    const float* head_b1  = (const float*)d_in[17];
    const float* head_w2  = (const float*)d_in[18];
    const float* head_b2  = (const float*)d_in[19];

    float* ws   = (float*)d_ws;
    float* h    = ws + OFF_H;
    float* kker = ws + OFF_K;
    float* Ad   = ws + OFF_AD;
    float* invn = ws + OFF_INV;
    float* P  = h;
    float* Q  = h + 540672;
    float* Lb = h + 1064960;
    float* Rb = h + 3162112;
    float* qkb  = ws + OFF_MHA;
    float* qbb  = qkb + 2048;
    float* scb  = qbb + 16;
    float* attb = scb + 262144;
    float* ctxb = attb + 262144;

    k_build_ad<<<dim3(NLY), dim3(256), 0, stream>>>(s4logdt, Ad);
    k_pq_init<<<dim3(NLY), dim3(256), 0, stream>>>(Ad, P);
    for (int m = 1; m <= 5; ++m) {
        int half = 1 << (m - 1);
        k_mm64<<<dim3(half, NLY), dim3(256), 0, stream>>>(P, half, 33);
    }
    k_q_init<<<dim3(NLY), dim3(256), 0, stream>>>(P, Q);
    for (int m = 1; m <= 5; ++m) {
        int half = 1 << (m - 1);
        int cnt = (m == 5) ? 15 : half;
        k_mm64<<<dim3(cnt, NLY), dim3(256), 0, stream>>>(Q, half, 32);
    }
    k_lr<<<dim3(NLY * 64), dim3(256), 0, stream>>>(P, Q, s4B, s4C, Lb, Rb);
    k_kker<<<dim3(NLY * 256), dim3(256), 0, stream>>>(Lb, Rb, kker);

    k_embed<<<dim3(16, BB), dim3(256), 0, stream>>>(x, w_in, b_in, h);
    k_ln<<<dim3(16, BB), dim3(256), 0, stream>>>(h, ln_in_g, ln_in_b, h, invn, 1);

    for (int l = 0; l < NLY; ++l) {
        k_conv_mfma<<<dim3(DD, 2), dim3(256), 0, stream>>>(h, kker, invn, s4D, l);
        k_ln<<<dim3(16, BB), dim3(256), 0, stream>>>(h, ln_g + l * DD, ln_b + l * DD, h, invn, 0);
    }

    k_qprep<<<dim3(1), dim3(256), 0, stream>>>(cls, mha_in_w, mha_in_b, qkb, qbb);
    k_scores<<<dim3(4, BB), dim3(256), 0, stream>>>(h, cls, qkb, qbb, scb);
    k_softmax<<<dim3(256), dim3(256), 0, stream>>>(scb, attb);
    k_ctx<<<dim3(8, BB), dim3(256), 0, stream>>>(h, cls, attb, ctxb);
    k_head<<<dim3(BB), dim3(256), 0, stream>>>(ctxb, mha_in_w, mha_in_b, mha_out_w, mha_out_b,
                                               head_w1, head_b1, head_w2, head_b2, (float*)d_out);
}

// Round 4
// 1037.304 us; speedup vs baseline: 1.7736x; 1.1461x over previous
//
#include <hip/hip_runtime.h>

#define BB 32
#define CC 129
#define TT 1000
#define DD 256
#define NN 64
#define NLY 4

// ---------------- workspace layout (floats) ----------------
#define OFF_H    0
#define OFF_K    8192000
#define OFF_AD   9216000
#define OFF_INV  9232384
#define OFF_MHA  9264384

typedef __attribute__((ext_vector_type(8))) short bf16x8;
typedef __attribute__((ext_vector_type(4))) float f32x4;

__device__ __forceinline__ unsigned short f2bf(float x) {
    unsigned int u = __float_as_uint(x);
    unsigned int r = (u + 0x7FFF + ((u >> 16) & 1)) >> 16;
    return (unsigned short)r;
}
__device__ __forceinline__ float bf2f(unsigned short b) {
    return __uint_as_float(((unsigned int)b) << 16);
}

// ============ Ad = (I - dtA/2)^-1 (I + dtA/2), Gauss-Jordan w/ partial pivot ============
#define ST 131
__global__ __launch_bounds__(256) void k_build_ad(const float* __restrict__ logdt,
                                                  float* __restrict__ Ad) {
    __shared__ float M[64 * ST];
    __shared__ int piv;
    int l = blockIdx.x;
    int tid = threadIdx.x;
    int q = tid >> 6, r = tid & 63;
    float dt = expf(logdt[l * DD]);
    dt = fminf(fmaxf(dt, 1e-4f), 0.1f);
    float hh = dt * 0.5f;
    float Pr = sqrtf(1.f + 2.f * (float)r);
    for (int j = q; j < 130; j += 4) {
        int jj = (j < 64) ? j : (j - 64);
        float a;
        if (r == jj) a = -((float)r + 0.5f);
        else { float m = Pr * sqrtf(1.f + 2.f * (float)jj); a = (r > jj) ? -m : m; }
        float ident = (r == jj) ? 1.f : 0.f;
        M[r * ST + j] = (j < 64) ? (ident - hh * a) : (ident + hh * a);
    }
    __syncthreads();
    for (int c = 0; c < 64; ++c) {
        if (tid < 64) {
            float bv = (r >= c) ? fabsf(M[r * ST + c]) : -1.f;
            int bi = r;
            for (int off = 32; off; off >>= 1) {
                float ov = __shfl_xor(bv, off);
                int oi = __shfl_xor(bi, off);
                if (ov > bv) { bv = ov; bi = oi; }
            }
            if (tid == 0) piv = bi;
        }
        __syncthreads();
        int p = piv;
        if (tid >= c && tid < 130) {
            float pv = M[p * ST + c];
            float inv = 1.f / pv;
            if (p != c) {
                float a = M[c * ST + tid], b2 = M[p * ST + tid];
                M[p * ST + tid] = a;
                M[c * ST + tid] = (tid > c) ? b2 * inv : b2;
            } else if (tid > c) {
                M[c * ST + tid] *= inv;
            }
        }
        __syncthreads();
        if (r != c) {
            float f = M[r * ST + c];
            int base = c + 1;
            int j0 = base + (((q - base) % 4) + 4) % 4;
            for (int j = j0; j < 130; j += 4)
                M[r * ST + j] = fmaf(-f, M[c * ST + j], M[r * ST + j]);
        }
        __syncthreads();
    }
    for (int i = tid; i < 4096; i += 256) {
        int rr = i >> 6, j = i & 63;
        Ad[(l * 64 + rr) * 64 + j] = M[rr * ST + 64 + j];
    }
}

// ============ power tree ============
__global__ __launch_bounds__(256) void k_pq_init(const float* __restrict__ Ad, float* __restrict__ P) {
    int l = blockIdx.x;
    for (int i = threadIdx.x; i < 4096; i += 256) {
        int r = i >> 6, c = i & 63;
        P[(l * 33 + 0) * 4096 + i] = (r == c) ? 1.f : 0.f;
        P[(l * 33 + 1) * 4096 + i] = Ad[l * 4096 + i];
    }
}

__global__ __launch_bounds__(256) void k_q_init(const float* __restrict__ P, float* __restrict__ Q) {
    int l = blockIdx.x;
    for (int i = threadIdx.x; i < 4096; i += 256) {
        int r = i >> 6, c = i & 63;
        Q[(l * 32 + 0) * 4096 + i] = (r == c) ? 1.f : 0.f;
        Q[(l * 32 + 1) * 4096 + i] = P[(l * 33 + 32) * 4096 + i];
    }
}

__global__ __launch_bounds__(256) void k_mm64(float* __restrict__ base, int half, int smats) {
    __shared__ float As[4096], Bs[4096];
    int l = blockIdx.y;
    int j = half + 1 + blockIdx.x;
    const float* Am = base + (size_t)(l * smats + half) * 4096;
    const float* Bm = base + (size_t)(l * smats + (j - half)) * 4096;
    float* Dm = base + (size_t)(l * smats + j) * 4096;
    for (int i = threadIdx.x; i < 4096; i += 256) { As[i] = Am[i]; Bs[i] = Bm[i]; }
    __syncthreads();
    int tr = (threadIdx.x >> 4) << 2;
    int tc = (threadIdx.x & 15) << 2;
    float acc[4][4];
#pragma unroll
    for (int u = 0; u < 4; ++u)
#pragma unroll
        for (int v = 0; v < 4; ++v) acc[u][v] = 0.f;
    for (int k = 0; k < 64; ++k) {
        float a0 = As[(tr + 0) * 64 + k], a1 = As[(tr + 1) * 64 + k];
        float a2 = As[(tr + 2) * 64 + k], a3 = As[(tr + 3) * 64 + k];
        float b0 = Bs[k * 64 + tc + 0], b1 = Bs[k * 64 + tc + 1];
        float b2 = Bs[k * 64 + tc + 2], b3 = Bs[k * 64 + tc + 3];
        acc[0][0] = fmaf(a0, b0, acc[0][0]); acc[0][1] = fmaf(a0, b1, acc[0][1]);
        acc[0][2] = fmaf(a0, b2, acc[0][2]); acc[0][3] = fmaf(a0, b3, acc[0][3]);
        acc[1][0] = fmaf(a1, b0, acc[1][0]); acc[1][1] = fmaf(a1, b1, acc[1][1]);
        acc[1][2] = fmaf(a1, b2, acc[1][2]); acc[1][3] = fmaf(a1, b3, acc[1][3]);
        acc[2][0] = fmaf(a2, b0, acc[2][0]); acc[2][1] = fmaf(a2, b1, acc[2][1]);
        acc[2][2] = fmaf(a2, b2, acc[2][2]); acc[2][3] = fmaf(a2, b3, acc[2][3]);
        acc[3][0] = fmaf(a3, b0, acc[3][0]); acc[3][1] = fmaf(a3, b1, acc[3][1]);
        acc[3][2] = fmaf(a3, b2, acc[3][2]); acc[3][3] = fmaf(a3, b3, acc[3][3]);
    }
#pragma unroll
    for (int u = 0; u < 4; ++u)
#pragma unroll
        for (int v = 0; v < 4; ++v) Dm[(tr + u) * 64 + tc + v] = acc[u][v];
}

// ============ L / R ============
__global__ __launch_bounds__(256) void k_lr(const float* __restrict__ P, const float* __restrict__ Q,
                                            const float* __restrict__ s4B, const float* __restrict__ s4C,
                                            float* __restrict__ L, float* __restrict__ R) {
    __shared__ float Ms[4096];
    int l = blockIdx.x >> 6, rem = blockIdx.x & 63, which = rem >> 5, idx = rem & 31;
    const float* M = which ? (P + (size_t)(l * 33 + idx) * 4096)
                           : (Q + (size_t)(l * 32 + idx) * 4096);
    for (int i = threadIdx.x; i < 4096; i += 256) Ms[i] = M[i];
    __syncthreads();
    int d = threadIdx.x;
    if (which == 0) {
        float* dst = L + (((size_t)(l * DD + d) * 32 + idx) * 64);
        for (int jc = 0; jc < 8; ++jc) {
            float acc[8];
#pragma unroll
            for (int u = 0; u < 8; ++u) acc[u] = 0.f;
            for (int i = 0; i < 64; ++i) {
                float bv = s4B[(l * NN + i) * DD + d];
#pragma unroll
                for (int u = 0; u < 8; ++u)
                    acc[u] = fmaf(bv, Ms[i * 64 + jc * 8 + u], acc[u]);
            }
#pragma unroll
            for (int u = 0; u < 8; ++u) dst[jc * 8 + u] = acc[u];
        }
    } else {
        float* dst = R + (((size_t)(l * DD + d) * 32 + idx) * 64);
        const float* Cp = s4C + (size_t)(l * DD + d) * NN;
        for (int ic = 0; ic < 8; ++ic) {
            float acc[8];
#pragma unroll
            for (int u = 0; u < 8; ++u) acc[u] = 0.f;
            for (int j = 0; j < 64; ++j) {
                float cv = Cp[j];
#pragma unroll
                for (int u = 0; u < 8; ++u)
                    acc[u] = fmaf(Ms[(ic * 8 + u) * 64 + j], cv, acc[u]);
            }
#pragma unroll
            for (int u = 0; u < 8; ++u) dst[ic * 8 + u] = acc[u];
        }
    }
}

// ============ kernel assembly ============
__global__ __launch_bounds__(256) void k_kker(const float* __restrict__ L, const float* __restrict__ R,
                                              float* __restrict__ kk) {
    __shared__ float Ls[32 * 65], Rs[32 * 65];
    int l = blockIdx.x >> 8, d = blockIdx.x & 255;
    const float* Lp = L + ((size_t)(l * DD + d) * 32) * 64;
    const float* Rp = R + ((size_t)(l * DD + d) * 32) * 64;
    for (int i = threadIdx.x; i < 2048; i += 256) {
        int row = i >> 6, col = i & 63;
        Ls[row * 65 + col] = Lp[i];
        Rs[row * 65 + col] = Rp[i];
    }
    __syncthreads();
    for (int t = threadIdx.x; t < TT; t += 256) {
        int kq = t >> 5, r = t & 31;
        const float* lr = &Ls[kq * 65];
        const float* rr = &Rs[r * 65];
        float a = 0.f;
#pragma unroll 8
        for (int m = 0; m < 64; ++m) a = fmaf(lr[m], rr[m], a);
        kk[(size_t)(l * DD + d) * TT + t] = a * expf(-0.01f * (float)t);
    }
}

// ============ w_in -> split-bf16, padded stride 136 (16B-aligned fragments) ============
__global__ __launch_bounds__(64) void k_wprep(const float* __restrict__ w_in,
                                              unsigned short* __restrict__ whi,
                                              unsigned short* __restrict__ wlo) {
    int d = blockIdx.x;
    for (int c = threadIdx.x; c < 136; c += 64) {
        float v = (c < CC) ? w_in[d * CC + c] : 0.f;
        unsigned short h = f2bf(v);
        whi[d * 136 + c] = h;
        wlo[d * 136 + c] = f2bf(v - bf2f(h));
    }
}

// ============ MFMA embed: h[b,d,t] = sum_c w[d,c] x[b,c,t] + b_in[d] ============
// GEMM M=256(d) K=129(c) N=64(t per block). A = w (split-bf16, global, 16B frags),
// B = x-tile transposed [t][c] in LDS (word-stride 65 = odd -> 2-way conflicts only).
// K-chunks c=0..127 via MFMA; c=128 + bias folded into epilogue.
__global__ __launch_bounds__(256) void k_embed_mfma(const float* __restrict__ x,
                                                    const unsigned short* __restrict__ whi,
                                                    const unsigned short* __restrict__ wlo,
                                                    const float* __restrict__ w_in,
                                                    const float* __restrict__ b_in,
                                                    float* __restrict__ h) {
    __shared__ unsigned short xs_h[64 * 130], xs_l[64 * 130];
    __shared__ float xlasts[64], w128s[256], biass[256];
    int b = blockIdx.y, t0 = blockIdx.x * 64;
    int tid = threadIdx.x;
    for (int i = tid; i < CC * 64; i += 256) {
        int c = i >> 6, tl = i & 63;
        int t = t0 + tl;
        float v = (t < TT) ? x[(size_t)(b * CC + c) * TT + t] : 0.f;
        if (c == 128) {
            xlasts[tl] = v;
        } else {
            unsigned short hh = f2bf(v);
            xs_h[tl * 130 + c] = hh;
            xs_l[tl * 130 + c] = f2bf(v - bf2f(hh));
        }
    }
    w128s[tid] = w_in[tid * CC + 128];
    biass[tid] = b_in[tid];
    __syncthreads();
    int wave = tid >> 6, lane = tid & 63;
    int tn = lane & 15, q = lane >> 4;
    int d0w = wave * 64;
    f32x4 acc[4][4];
#pragma unroll
    for (int nt = 0; nt < 4; ++nt)
#pragma unroll
        for (int mt = 0; mt < 4; ++mt) acc[nt][mt] = (f32x4){0.f, 0.f, 0.f, 0.f};
#pragma unroll
    for (int kc = 0; kc < 4; ++kc) {
        int c0 = kc * 32;
        bf16x8 Ah[4], Al[4];
#pragma unroll
        for (int mt = 0; mt < 4; ++mt) {
            int base = (d0w + mt * 16 + tn) * 136 + c0 + 8 * q;
            Ah[mt] = *(const bf16x8*)&whi[base];
            Al[mt] = *(const bf16x8*)&wlo[base];
        }
#pragma unroll
        for (int nt = 0; nt < 4; ++nt) {
            const unsigned int* ph = (const unsigned int*)&xs_h[(nt * 16 + tn) * 130 + c0 + 8 * q];
            const unsigned int* pl = (const unsigned int*)&xs_l[(nt * 16 + tn) * 130 + c0 + 8 * q];
            union { bf16x8 v; unsigned int u[4]; } Bh, Bl;
            Bh.u[0] = ph[0]; Bh.u[1] = ph[1]; Bh.u[2] = ph[2]; Bh.u[3] = ph[3];
            Bl.u[0] = pl[0]; Bl.u[1] = pl[1]; Bl.u[2] = pl[2]; Bl.u[3] = pl[3];
#pragma unroll
            for (int mt = 0; mt < 4; ++mt) {
                acc[nt][mt] = __builtin_amdgcn_mfma_f32_16x16x32_bf16(Al[mt], Bh.v, acc[nt][mt], 0, 0, 0);
                acc[nt][mt] = __builtin_amdgcn_mfma_f32_16x16x32_bf16(Ah[mt], Bl.v, acc[nt][mt], 0, 0, 0);
                acc[nt][mt] = __builtin_amdgcn_mfma_f32_16x16x32_bf16(Ah[mt], Bh.v, acc[nt][mt], 0, 0, 0);
            }
        }
    }
#pragma unroll
    for (int nt = 0; nt < 4; ++nt) {
        int t = t0 + nt * 16 + tn;
        if (t >= TT) continue;
        float xl = xlasts[nt * 16 + tn];
#pragma unroll
        for (int mt = 0; mt < 4; ++mt) {
#pragma unroll
            for (int r = 0; r < 4; ++r) {
                int d = d0w + mt * 16 + 4 * q + r;
                h[((size_t)(b * DD + d)) * TT + t] = acc[nt][mt][r] + biass[d] + w128s[d] * xl;
            }
        }
    }
}

// ============ LayerNorm over d (in-place), optional +pos-encoding, fused invn ============
__global__ __launch_bounds__(256) void k_ln(const float* __restrict__ in, const float* __restrict__ g,
                                            const float* __restrict__ bia, float* __restrict__ out,
                                            float* __restrict__ invn, int add_pe) {
    int b = blockIdx.y, t0 = blockIdx.x * 64;
    int w = threadIdx.x >> 6, lane = threadIdx.x & 63;
    int t = t0 + lane;
    __shared__ float ps[4][64], ps2[4][64];
    float s = 0.f, s2 = 0.f;
    if (t < TT)
        for (int d = w; d < DD; d += 4) {
            float v = in[(size_t)(b * DD + d) * TT + t];
            s += v; s2 = fmaf(v, v, s2);
        }
    ps[w][lane] = s; ps2[w][lane] = s2;
    __syncthreads();
    float mean = (ps[0][lane] + ps[1][lane] + ps[2][lane] + ps[3][lane]) * (1.f / 256.f);
    float ex2  = (ps2[0][lane] + ps2[1][lane] + ps2[2][lane] + ps2[3][lane]) * (1.f / 256.f);
    float rstd = 1.f / sqrtf(ex2 - mean * mean + 1e-5f);
    float sq = 0.f;
    if (t < TT) {
        float ft = (float)t;
        for (int d = w; d < DD; d += 4) {
            size_t ix = (size_t)(b * DD + d) * TT + t;
            float v = in[ix];
            float o = (v - mean) * rstd * g[d] + bia[d];
            if (add_pe) {
                float freq = expf((float)(d & ~1) * (-9.210340371976184f / 256.f));
                float ang = ft * freq;
                o += (d & 1) ? cosf(ang) : sinf(ang);
            }
            out[ix] = o;
            sq = fmaf(o, o, sq);
        }
    }
    __syncthreads();
    ps[w][lane] = sq;
    __syncthreads();
    if (w == 0 && t < TT) {
        float tot = ps[0][lane] + ps[1][lane] + ps[2][lane] + ps[3][lane];
        invn[b * TT + t] = 1.f / (sqrtf(tot) + 1e-8f);
    }
}

__device__ __forceinline__ float gelu_exact(float y) {
    return 0.5f * y * (1.f + erff(y * 0.7071067811865476f));
}

// ============ MFMA conv: C[b,t] = sum_u Xn[b][u] * k[(t0+t)-(u0+u)] ============
#define XSTR 1032
__global__ __launch_bounds__(256) void k_conv_mfma(float* __restrict__ h, const float* __restrict__ kk,
                                                   const float* __restrict__ invn,
                                                   const float* __restrict__ s4D, int layer) {
    __shared__ unsigned short Xh[16 * XSTR], Xl[16 * XSTR];
    __shared__ unsigned int pkh[1040], pkl[1040];
    int d = blockIdx.x, b0 = blockIdx.y * 16;
    int tid = threadIdx.x;
    const float* krow = kk + (size_t)(layer * DD + d) * TT;
    for (int mm = tid; mm < 1040; mm += 256) {
        int m = mm - 32;
        float klo = (m >= 0 && m < TT) ? krow[m] : 0.f;
        float kpr = (m >= 1 && m <= TT) ? krow[m - 1] : 0.f;
        unsigned short lh = f2bf(klo); unsigned short ll = f2bf(klo - bf2f(lh));
        unsigned short ph = f2bf(kpr); unsigned short pl = f2bf(kpr - bf2f(ph));
        pkh[mm] = (unsigned int)lh | ((unsigned int)ph << 16);
        pkl[mm] = (unsigned int)ll | ((unsigned int)pl << 16);
    }
    for (int i = tid; i < 16 * 1024; i += 256) {
        int bb = i >> 10, t = i & 1023;
        float v = 0.f;
        if (t < TT)
            v = h[((size_t)(b0 + bb) * DD + d) * TT + t] * invn[(b0 + bb) * TT + t];
        unsigned short vh = f2bf(v);
        unsigned short vl = f2bf(v - bf2f(vh));
        Xh[bb * XSTR + t] = vh;
        Xl[bb * XSTR + t] = vl;
    }
    __syncthreads();
    float gate = 1.f / (1.f + expf(-s4D[layer * DD + d]));
    int wave = tid >> 6, lane = tid & 63;
    int tn = lane & 15, qq = lane >> 4;
    for (int j = wave; j < 63; j += 4) {
        int t0 = j * 16;
        f32x4 acc1 = {0.f, 0.f, 0.f, 0.f};
        f32x4 acc2 = {0.f, 0.f, 0.f, 0.f};
        f32x4 acc3 = {0.f, 0.f, 0.f, 0.f};
        for (int u0 = 0; u0 <= t0 + 15; u0 += 32) {
            const bf16x8 ah = *(const bf16x8*)&Xh[tn * XSTR + u0 + 8 * qq];
            const bf16x8 al = *(const bf16x8*)&Xl[tn * XSTR + u0 + 8 * qq];
            int S32 = t0 - u0 + tn - 8 * qq + 32;
            union { bf16x8 v; unsigned int u[4]; } bh, bl;
            bh.u[0] = pkh[S32];     bl.u[0] = pkl[S32];
            bh.u[1] = pkh[S32 - 2]; bl.u[1] = pkl[S32 - 2];
            bh.u[2] = pkh[S32 - 4]; bl.u[2] = pkl[S32 - 4];
            bh.u[3] = pkh[S32 - 6]; bl.u[3] = pkl[S32 - 6];
            acc1 = __builtin_amdgcn_mfma_f32_16x16x32_bf16(ah, bh.v, acc1, 0, 0, 0);
            acc2 = __builtin_amdgcn_mfma_f32_16x16x32_bf16(ah, bl.v, acc2, 0, 0, 0);
            acc3 = __builtin_amdgcn_mfma_f32_16x16x32_bf16(al, bh.v, acc3, 0, 0, 0);
        }
        int t = t0 + tn;
        if (t < TT) {
#pragma unroll
            for (int r = 0; r < 4; ++r) {
                int brow = 4 * qq + r;
                size_t ix = ((size_t)(b0 + brow) * DD + d) * TT + t;
                float y = acc1[r] + acc2[r] + acc3[r];
                float xn = bf2f(Xh[brow * XSTR + t]) + bf2f(Xl[brow * XSTR + t]);
                float ho = xn / invn[(b0 + brow) * TT + t];   // reconstruct h (no HBM re-read)
                h[ix] = gelu_exact(y + xn * gate) + 1.1f * ho;
            }
        }
    }
}

// ============ MHA pooling ============
__global__ __launch_bounds__(256) void k_qprep(const float* __restrict__ cls, const float* __restrict__ inw,
                                               const float* __restrict__ inb, float* __restrict__ qk,
                                               float* __restrict__ qb) {
    __shared__ float Qv[256];
    int j = threadIdx.x;
    float a = inb[j];
    for (int i = 0; i < 256; ++i) a = fmaf(inw[j * DD + i], cls[i], a);
    Qv[j] = a;
    __syncthreads();
    const float scale = 0.17677669529663687f; // 1/sqrt(32)
    for (int idx = threadIdx.x; idx < 8 * 256; idx += 256) {
        int hh = idx >> 8, i = idx & 255;
        float s = 0.f;
        for (int jj = 0; jj < 32; ++jj)
            s = fmaf(Qv[hh * 32 + jj], inw[(DD + hh * 32 + jj) * DD + i], s);
        qk[idx] = s * scale;
    }
    if (threadIdx.x < 8) {
        int hh = threadIdx.x;
        float s = 0.f;
        for (int jj = 0; jj < 32; ++jj)
            s = fmaf(Qv[hh * 32 + jj], inb[DD + hh * 32 + jj], s);
        qb[hh] = s * scale;
    }
}

__global__ __launch_bounds__(256) void k_scores(const float* __restrict__ h, const float* __restrict__ cls,
                                                const float* __restrict__ qkw, const float* __restrict__ qbw,
                                                float* __restrict__ sc) {
    __shared__ float qks[8 * 256];
    int b = blockIdx.y;
    int s = blockIdx.x * 256 + threadIdx.x;
    for (int i = threadIdx.x; i < 2048; i += 256) qks[i] = qkw[i];
    __syncthreads();
    if (s >= TT + 1) return;
    float acc[8];
#pragma unroll
    for (int hh = 0; hh < 8; ++hh) acc[hh] = qbw[hh];
    if (s == 0) {
        for (int i = 0; i < 256; ++i) {
            float v = cls[i];
#pragma unroll
            for (int hh = 0; hh < 8; ++hh) acc[hh] = fmaf(qks[hh * 256 + i], v, acc[hh]);
        }
    } else {
        const float* hb = h + (size_t)b * DD * TT + (s - 1);
        for (int i = 0; i < 256; ++i) {
            float v = hb[(size_t)i * TT];
#pragma unroll
            for (int hh = 0; hh < 8; ++hh) acc[hh] = fmaf(qks[hh * 256 + i], v, acc[hh]);
        }
    }
#pragma unroll
    for (int hh = 0; hh < 8; ++hh) sc[(size_t)(b * 8 + hh) * 1024 + s] = acc[hh];
}

__global__ __launch_bounds__(256) void k_softmax(const float* __restrict__ sc, float* __restrict__ att) {
    int row = blockIdx.x;
    const float* p = sc + (size_t)row * 1024;
    float* o = att + (size_t)row * 1024;
    __shared__ float red[256];
    float m = -3.4e38f;
    for (int s = threadIdx.x; s < TT + 1; s += 256) m = fmaxf(m, p[s]);
    red[threadIdx.x] = m; __syncthreads();
    for (int st = 128; st; st >>= 1) {
        if (threadIdx.x < st) red[threadIdx.x] = fmaxf(red[threadIdx.x], red[threadIdx.x + st]);
        __syncthreads();
    }
    m = red[0]; __syncthreads();
    float sum = 0.f;
    for (int s = threadIdx.x; s < TT + 1; s += 256) {
        float e = expf(p[s] - m);
        o[s] = e; sum += e;
    }
    red[threadIdx.x] = sum; __syncthreads();
    for (int st = 128; st; st >>= 1) {
        if (threadIdx.x < st) red[threadIdx.x] += red[threadIdx.x + st];
        __syncthreads();
    }
    float inv = 1.f / red[0];
    for (int s = threadIdx.x; s < TT + 1; s += 256) o[s] *= inv;
}

__global__ __launch_bounds__(256) void k_ctx(const float* __restrict__ h, const float* __restrict__ cls,
                                             const float* __restrict__ att, float* __restrict__ ctx) {
    __shared__ float as[8][1024];
    int b = blockIdx.y, i0 = blockIdx.x * 32;
    for (int idx = threadIdx.x; idx < 8 * 1024; idx += 256) {
        int hh = idx >> 10, s = idx & 1023;
        as[hh][s] = (s < TT + 1) ? att[(size_t)(b * 8 + hh) * 1024 + s] : 0.f;
    }
    __syncthreads();
    int w = threadIdx.x >> 6, lane = threadIdx.x & 63;
    for (int ii = 0; ii < 8; ++ii) {
        int i = i0 + w * 8 + ii;
        const float* hb = h + (size_t)(b * DD + i) * TT;
        float acc[8];
#pragma unroll
        for (int hh = 0; hh < 8; ++hh) acc[hh] = 0.f;
        for (int t = lane; t < TT; t += 64) {
            float v = hb[t];
#pragma unroll
            for (int hh = 0; hh < 8; ++hh) acc[hh] = fmaf(as[hh][t + 1], v, acc[hh]);
        }
#pragma unroll
        for (int off = 32; off; off >>= 1)
#pragma unroll
            for (int hh = 0; hh < 8; ++hh) acc[hh] += __shfl_down(acc[hh], off);
        if (lane == 0) {
#pragma unroll
            for (int hh = 0; hh < 8; ++hh)
                ctx[(size_t)(b * 8 + hh) * DD + i] = acc[hh] + as[hh][0] * cls[i];
        }
    }
}

__global__ __launch_bounds__(256) void k_head(const float* __restrict__ ctx, const float* __restrict__ inw,
                                              const float* __restrict__ inb, const float* __restrict__ outw,
                                              const float* __restrict__ outb, const float* __restrict__ w1,
                                              const float* __restrict__ b1, const float* __restrict__ w2,
                                              const float* __restrict__ b2, float* __restrict__ out) {
    int b = blockIdx.x;
    __shared__ float cs[2048], ao[256], po[256], hid[128];
    for (int i = threadIdx.x; i < 2048; i += 256) cs[i] = ctx[(size_t)b * 2048 + i];
    __syncthreads();
    int j = threadIdx.x;
    {
        int hh = j >> 5;
        float a = inb[2 * DD + j];
        const float* wv = inw + (size_t)(2 * DD + j) * DD;
        for (int i = 0; i < 256; ++i) a = fmaf(wv[i], cs[hh * 256 + i], a);
        ao[j] = a;
    }
    __syncthreads();
    {
        float a = outb[j];
        for (int i = 0; i < 256; ++i) a = fmaf(outw[j * DD + i], ao[i], a);
        po[j] = a;
    }
    __syncthreads();
    if (j < 128) {
        float a = b1[j];
        for (int i = 0; i < 256; ++i) a = fmaf(w1[j * 256 + i], po[i], a);
        hid[j] = fmaxf(a, 0.f);
    }
    __syncthreads();
    if (j == 0) {
        float a = b2[0];
        for (int i = 0; i < 128; ++i) a = fmaf(w2[i], hid[i], a);
        out[b] = a;
    }
}

extern "C" void kernel_launch(void* const* d_in, const int* in_sizes, int n_in,
                              void* d_out, int out_size, void* d_ws, size_t ws_size,
                              hipStream_t stream) {
    (void)in_sizes; (void)n_in; (void)out_size; (void)ws_size;
    const float* x        = (const float*)d_in[0];
    const float* w_in     = (const float*)d_in[1];
    const float* b_in     = (const float*)d_in[2];
    const float* ln_in_g  = (const float*)d_in[3];
    const float* ln_in_b  = (const float*)d_in[4];
    const float* s4B      = (const float*)d_in[5];
    const float* s4C      = (const float*)d_in[6];
    const float* s4logdt  = (const float*)d_in[7];
    const float* s4D      = (const float*)d_in[8];
    const float* ln_g     = (const float*)d_in[9];
    const float* ln_b     = (const float*)d_in[10];
    const float* cls      = (const float*)d_in[11];
    const float* mha_in_w = (const float*)d_in[12];
    const float* mha_in_b = (const float*)d_in[13];
    const float* mha_out_w= (const float*)d_in[14];
    const float* mha_out_b= (const float*)d_in[15];
    const float* head_w1  = (const float*)d_in[16];
    const float* head_b1  = (const float*)d_in[17];
    const float* head_w2  = (const float*)d_in[18];
    const float* head_b2  = (const float*)d_in[19];

    float* ws   = (float*)d_ws;
    float* h    = ws + OFF_H;
    float* kker = ws + OFF_K;
    float* Ad   = ws + OFF_AD;
    float* invn = ws + OFF_INV;
    float* P  = h;
    float* Q  = h + 540672;
    float* Lb = h + 1064960;
    float* Rb = h + 3162112;
    float* qkb  = ws + OFF_MHA;
    float* qbb  = qkb + 2048;
    float* scb  = qbb + 16;
    float* attb = scb + 262144;
    float* ctxb = attb + 262144;
    // w split-bf16 overlaid on sc region (sc not live until MHA; whi dead by then)
    unsigned short* whi = (unsigned short*)scb;
    unsigned short* wlo = whi + 256 * 136;

    k_wprep<<<dim3(256), dim3(64), 0, stream>>>(w_in, whi, wlo);
    k_build_ad<<<dim3(NLY), dim3(256), 0, stream>>>(s4logdt, Ad);
    k_pq_init<<<dim3(NLY), dim3(256), 0, stream>>>(Ad, P);
    for (int m = 1; m <= 5; ++m) {
        int half = 1 << (m - 1);
        k_mm64<<<dim3(half, NLY), dim3(256), 0, stream>>>(P, half, 33);
    }
    k_q_init<<<dim3(NLY), dim3(256), 0, stream>>>(P, Q);
    for (int m = 1; m <= 5; ++m) {
        int half = 1 << (m - 1);
        int cnt = (m == 5) ? 15 : half;
        k_mm64<<<dim3(cnt, NLY), dim3(256), 0, stream>>>(Q, half, 32);
    }
    k_lr<<<dim3(NLY * 64), dim3(256), 0, stream>>>(P, Q, s4B, s4C, Lb, Rb);
    k_kker<<<dim3(NLY * 256), dim3(256), 0, stream>>>(Lb, Rb, kker);

    k_embed_mfma<<<dim3(16, BB), dim3(256), 0, stream>>>(x, whi, wlo, w_in, b_in, h);
    k_ln<<<dim3(16, BB), dim3(256), 0, stream>>>(h, ln_in_g, ln_in_b, h, invn, 1);

    for (int l = 0; l < NLY; ++l) {
        k_conv_mfma<<<dim3(DD, 2), dim3(256), 0, stream>>>(h, kker, invn, s4D, l);
        k_ln<<<dim3(16, BB), dim3(256), 0, stream>>>(h, ln_g + l * DD, ln_b + l * DD, h, invn, 0);
    }

    k_qprep<<<dim3(1), dim3(256), 0, stream>>>(cls, mha_in_w, mha_in_b, qkb, qbb);
    k_scores<<<dim3(4, BB), dim3(256), 0, stream>>>(h, cls, qkb, qbb, scb);
    k_softmax<<<dim3(256), dim3(256), 0, stream>>>(scb, attb);
    k_ctx<<<dim3(8, BB), dim3(256), 0, stream>>>(h, cls, attb, ctxb);
    k_head<<<dim3(BB), dim3(256), 0, stream>>>(ctxb, mha_in_w, mha_in_b, mha_out_w, mha_out_b,
                                               head_w1, head_b1, head_w2, head_b2, (float*)d_out);
}

// Round 5
// 966.380 us; speedup vs baseline: 1.9038x; 1.0734x over previous
//
#include <hip/hip_runtime.h>

#define BB 32
#define CC 129
#define TT 1000
#define DD 256
#define NN 64
#define NLY 4

// ---------------- workspace layout (floats) ----------------
#define OFF_H    0
#define OFF_K    8192000
#define OFF_INV  9232384
#define OFF_MHA  9264384

typedef __attribute__((ext_vector_type(8))) short bf16x8;
typedef __attribute__((ext_vector_type(4))) float f32x4;

__device__ __forceinline__ unsigned short f2bf(float x) {
    unsigned int u = __float_as_uint(x);
    unsigned int r = (u + 0x7FFF + ((u >> 16) & 1)) >> 16;
    return (unsigned short)r;
}
__device__ __forceinline__ float bf2f(unsigned short b) {
    return __uint_as_float(((unsigned int)b) << 16);
}

// ============ Ad = (I - hhA)^-1 (I + hhA) = 2(I-hhA)^-1 - I ============
// Register-resident Gauss-Jordan, one wave per layer, lane = row, zero barriers.
// No pivoting: sym(I-hhA) = diag(1+hh(i+0.5)) >= I -> pivots >= 1 (PD-part closed
// under Schur complement), and dt=1e-3 makes M ~ I anyway.
// RHS = 2I; writes P0 = I, P1 = Ad directly (k_pq_init folded in).
__global__ __launch_bounds__(64) void k_build_ad(const float* __restrict__ logdt,
                                                 float* __restrict__ P) {
    int l = blockIdx.x;
    int r = threadIdx.x;
    float dt = expf(logdt[l * DD]);
    dt = fminf(fmaxf(dt, 1e-4f), 0.1f);
    float hh = dt * 0.5f;
    float Pr = sqrtf(1.f + 2.f * (float)r);
    float col[130];
#pragma unroll
    for (int j = 0; j < 64; ++j) {
        float a;
        if (r == j) a = -((float)r + 0.5f);
        else { float m = Pr * sqrtf(1.f + 2.f * (float)j); a = (r > j) ? -m : m; }
        col[j] = ((r == j) ? 1.f : 0.f) - hh * a;
        col[64 + j] = (r == j) ? 2.f : 0.f;
    }
#pragma unroll
    for (int c = 0; c < 64; ++c) {
        float pvc = __shfl(col[c], c);
        float inv = 1.f / pvc;
        float g = col[c];
        bool isp = (r == c);
#pragma unroll
        for (int j = c + 1; j < 64; ++j) {
            float pv = __shfl(col[j], c) * inv;
            col[j] = isp ? pv : fmaf(-g, pv, col[j]);
        }
#pragma unroll
        for (int j = 64; j <= 64 + c; ++j) {
            float pv = __shfl(col[j], c) * inv;
            col[j] = isp ? pv : fmaf(-g, pv, col[j]);
        }
    }
    float* P0 = P + (size_t)(l * 33) * 4096 + r * 64;
    float* P1 = P + (size_t)(l * 33 + 1) * 4096 + r * 64;
#pragma unroll
    for (int j = 0; j < 64; ++j) {
        P0[j] = (r == j) ? 1.f : 0.f;
        P1[j] = col[64 + j] - ((r == j) ? 1.f : 0.f);
    }
}

// ============ power tree ============
__global__ __launch_bounds__(256) void k_q_init(const float* __restrict__ P, float* __restrict__ Q) {
    int l = blockIdx.x;
    for (int i = threadIdx.x; i < 4096; i += 256) {
        int r = i >> 6, c = i & 63;
        Q[(l * 32 + 0) * 4096 + i] = (r == c) ? 1.f : 0.f;
        Q[(l * 32 + 1) * 4096 + i] = P[(l * 33 + 32) * 4096 + i];
    }
}

__global__ __launch_bounds__(256) void k_mm64(float* __restrict__ base, int half, int smats) {
    __shared__ float As[4096], Bs[4096];
    int l = blockIdx.y;
    int j = half + 1 + blockIdx.x;
    const float* Am = base + (size_t)(l * smats + half) * 4096;
    const float* Bm = base + (size_t)(l * smats + (j - half)) * 4096;
    float* Dm = base + (size_t)(l * smats + j) * 4096;
    for (int i = threadIdx.x; i < 4096; i += 256) { As[i] = Am[i]; Bs[i] = Bm[i]; }
    __syncthreads();
    int tr = (threadIdx.x >> 4) << 2;
    int tc = (threadIdx.x & 15) << 2;
    float acc[4][4];
#pragma unroll
    for (int u = 0; u < 4; ++u)
#pragma unroll
        for (int v = 0; v < 4; ++v) acc[u][v] = 0.f;
    for (int k = 0; k < 64; ++k) {
        float a0 = As[(tr + 0) * 64 + k], a1 = As[(tr + 1) * 64 + k];
        float a2 = As[(tr + 2) * 64 + k], a3 = As[(tr + 3) * 64 + k];
        float b0 = Bs[k * 64 + tc + 0], b1 = Bs[k * 64 + tc + 1];
        float b2 = Bs[k * 64 + tc + 2], b3 = Bs[k * 64 + tc + 3];
        acc[0][0] = fmaf(a0, b0, acc[0][0]); acc[0][1] = fmaf(a0, b1, acc[0][1]);
        acc[0][2] = fmaf(a0, b2, acc[0][2]); acc[0][3] = fmaf(a0, b3, acc[0][3]);
        acc[1][0] = fmaf(a1, b0, acc[1][0]); acc[1][1] = fmaf(a1, b1, acc[1][1]);
        acc[1][2] = fmaf(a1, b2, acc[1][2]); acc[1][3] = fmaf(a1, b3, acc[1][3]);
        acc[2][0] = fmaf(a2, b0, acc[2][0]); acc[2][1] = fmaf(a2, b1, acc[2][1]);
        acc[2][2] = fmaf(a2, b2, acc[2][2]); acc[2][3] = fmaf(a2, b3, acc[2][3]);
        acc[3][0] = fmaf(a3, b0, acc[3][0]); acc[3][1] = fmaf(a3, b1, acc[3][1]);
        acc[3][2] = fmaf(a3, b2, acc[3][2]); acc[3][3] = fmaf(a3, b3, acc[3][3]);
    }
#pragma unroll
    for (int u = 0; u < 4; ++u)
#pragma unroll
        for (int v = 0; v < 4; ++v) Dm[(tr + u) * 64 + tc + v] = acc[u][v];
}

// ============ L / R ============
__global__ __launch_bounds__(256) void k_lr(const float* __restrict__ P, const float* __restrict__ Q,
                                            const float* __restrict__ s4B, const float* __restrict__ s4C,
                                            float* __restrict__ L, float* __restrict__ R) {
    __shared__ float Ms[4096];
    int l = blockIdx.x >> 6, rem = blockIdx.x & 63, which = rem >> 5, idx = rem & 31;
    const float* M = which ? (P + (size_t)(l * 33 + idx) * 4096)
                           : (Q + (size_t)(l * 32 + idx) * 4096);
    for (int i = threadIdx.x; i < 4096; i += 256) Ms[i] = M[i];
    __syncthreads();
    int d = threadIdx.x;
    if (which == 0) {
        float* dst = L + (((size_t)(l * DD + d) * 32 + idx) * 64);
        for (int jc = 0; jc < 8; ++jc) {
            float acc[8];
#pragma unroll
            for (int u = 0; u < 8; ++u) acc[u] = 0.f;
            for (int i = 0; i < 64; ++i) {
                float bv = s4B[(l * NN + i) * DD + d];
#pragma unroll
                for (int u = 0; u < 8; ++u)
                    acc[u] = fmaf(bv, Ms[i * 64 + jc * 8 + u], acc[u]);
            }
#pragma unroll
            for (int u = 0; u < 8; ++u) dst[jc * 8 + u] = acc[u];
        }
    } else {
        float* dst = R + (((size_t)(l * DD + d) * 32 + idx) * 64);
        const float* Cp = s4C + (size_t)(l * DD + d) * NN;
        for (int ic = 0; ic < 8; ++ic) {
            float acc[8];
#pragma unroll
            for (int u = 0; u < 8; ++u) acc[u] = 0.f;
            for (int j = 0; j < 64; ++j) {
                float cv = Cp[j];
#pragma unroll
                for (int u = 0; u < 8; ++u)
                    acc[u] = fmaf(Ms[(ic * 8 + u) * 64 + j], cv, acc[u]);
            }
#pragma unroll
            for (int u = 0; u < 8; ++u) dst[ic * 8 + u] = acc[u];
        }
    }
}

// ============ kernel assembly ============
__global__ __launch_bounds__(256) void k_kker(const float* __restrict__ L, const float* __restrict__ R,
                                              float* __restrict__ kk) {
    __shared__ float Ls[32 * 65], Rs[32 * 65];
    int l = blockIdx.x >> 8, d = blockIdx.x & 255;
    const float* Lp = L + ((size_t)(l * DD + d) * 32) * 64;
    const float* Rp = R + ((size_t)(l * DD + d) * 32) * 64;
    for (int i = threadIdx.x; i < 2048; i += 256) {
        int row = i >> 6, col = i & 63;
        Ls[row * 65 + col] = Lp[i];
        Rs[row * 65 + col] = Rp[i];
    }
    __syncthreads();
    for (int t = threadIdx.x; t < TT; t += 256) {
        int kq = t >> 5, r = t & 31;
        const float* lr = &Ls[kq * 65];
        const float* rr = &Rs[r * 65];
        float a = 0.f;
#pragma unroll 8
        for (int m = 0; m < 64; ++m) a = fmaf(lr[m], rr[m], a);
        kk[(size_t)(l * DD + d) * TT + t] = a * expf(-0.01f * (float)t);
    }
}

// ============ w_in -> split-bf16, padded stride 136 ============
__global__ __launch_bounds__(64) void k_wprep(const float* __restrict__ w_in,
                                              unsigned short* __restrict__ whi,
                                              unsigned short* __restrict__ wlo) {
    int d = blockIdx.x;
    for (int c = threadIdx.x; c < 136; c += 64) {
        float v = (c < CC) ? w_in[d * CC + c] : 0.f;
        unsigned short h = f2bf(v);
        whi[d * 136 + c] = h;
        wlo[d * 136 + c] = f2bf(v - bf2f(h));
    }
}

// ============ MFMA embed ============
__global__ __launch_bounds__(256) void k_embed_mfma(const float* __restrict__ x,
                                                    const unsigned short* __restrict__ whi,
                                                    const unsigned short* __restrict__ wlo,
                                                    const float* __restrict__ w_in,
                                                    const float* __restrict__ b_in,
                                                    float* __restrict__ h) {
    __shared__ unsigned short xs_h[64 * 130], xs_l[64 * 130];
    __shared__ float xlasts[64], w128s[256], biass[256];
    int b = blockIdx.y, t0 = blockIdx.x * 64;
    int tid = threadIdx.x;
    for (int i = tid; i < CC * 64; i += 256) {
        int c = i >> 6, tl = i & 63;
        int t = t0 + tl;
        float v = (t < TT) ? x[(size_t)(b * CC + c) * TT + t] : 0.f;
        if (c == 128) {
            xlasts[tl] = v;
        } else {
            unsigned short hh = f2bf(v);
            xs_h[tl * 130 + c] = hh;
            xs_l[tl * 130 + c] = f2bf(v - bf2f(hh));
        }
    }
    w128s[tid] = w_in[tid * CC + 128];
    biass[tid] = b_in[tid];
    __syncthreads();
    int wave = tid >> 6, lane = tid & 63;
    int tn = lane & 15, q = lane >> 4;
    int d0w = wave * 64;
    f32x4 acc[4][4];
#pragma unroll
    for (int nt = 0; nt < 4; ++nt)
#pragma unroll
        for (int mt = 0; mt < 4; ++mt) acc[nt][mt] = (f32x4){0.f, 0.f, 0.f, 0.f};
#pragma unroll
    for (int kc = 0; kc < 4; ++kc) {
        int c0 = kc * 32;
        bf16x8 Ah[4], Al[4];
#pragma unroll
        for (int mt = 0; mt < 4; ++mt) {
            int base = (d0w + mt * 16 + tn) * 136 + c0 + 8 * q;
            Ah[mt] = *(const bf16x8*)&whi[base];
            Al[mt] = *(const bf16x8*)&wlo[base];
        }
#pragma unroll
        for (int nt = 0; nt < 4; ++nt) {
            const unsigned int* ph = (const unsigned int*)&xs_h[(nt * 16 + tn) * 130 + c0 + 8 * q];
            const unsigned int* pl = (const unsigned int*)&xs_l[(nt * 16 + tn) * 130 + c0 + 8 * q];
            union { bf16x8 v; unsigned int u[4]; } Bh, Bl;
            Bh.u[0] = ph[0]; Bh.u[1] = ph[1]; Bh.u[2] = ph[2]; Bh.u[3] = ph[3];
            Bl.u[0] = pl[0]; Bl.u[1] = pl[1]; Bl.u[2] = pl[2]; Bl.u[3] = pl[3];
#pragma unroll
            for (int mt = 0; mt < 4; ++mt) {
                acc[nt][mt] = __builtin_amdgcn_mfma_f32_16x16x32_bf16(Al[mt], Bh.v, acc[nt][mt], 0, 0, 0);
                acc[nt][mt] = __builtin_amdgcn_mfma_f32_16x16x32_bf16(Ah[mt], Bl.v, acc[nt][mt], 0, 0, 0);
                acc[nt][mt] = __builtin_amdgcn_mfma_f32_16x16x32_bf16(Ah[mt], Bh.v, acc[nt][mt], 0, 0, 0);
            }
        }
    }
#pragma unroll
    for (int nt = 0; nt < 4; ++nt) {
        int t = t0 + nt * 16 + tn;
        if (t >= TT) continue;
        float xl = xlasts[nt * 16 + tn];
#pragma unroll
        for (int mt = 0; mt < 4; ++mt) {
#pragma unroll
            for (int r = 0; r < 4; ++r) {
                int d = d0w + mt * 16 + 4 * q + r;
                h[((size_t)(b * DD + d)) * TT + t] = acc[nt][mt][r] + biass[d] + w128s[d] * xl;
            }
        }
    }
}

// ============ LayerNorm (in-place), optional +pos-encoding, fused invn ============
__global__ __launch_bounds__(256) void k_ln(const float* __restrict__ in, const float* __restrict__ g,
                                            const float* __restrict__ bia, float* __restrict__ out,
                                            float* __restrict__ invn, int add_pe) {
    int b = blockIdx.y, t0 = blockIdx.x * 64;
    int w = threadIdx.x >> 6, lane = threadIdx.x & 63;
    int t = t0 + lane;
    __shared__ float ps[4][64], ps2[4][64];
    float s = 0.f, s2 = 0.f;
    if (t < TT)
        for (int d = w; d < DD; d += 4) {
            float v = in[(size_t)(b * DD + d) * TT + t];
            s += v; s2 = fmaf(v, v, s2);
        }
    ps[w][lane] = s; ps2[w][lane] = s2;
    __syncthreads();
    float mean = (ps[0][lane] + ps[1][lane] + ps[2][lane] + ps[3][lane]) * (1.f / 256.f);
    float ex2  = (ps2[0][lane] + ps2[1][lane] + ps2[2][lane] + ps2[3][lane]) * (1.f / 256.f);
    float rstd = 1.f / sqrtf(ex2 - mean * mean + 1e-5f);
    float sq = 0.f;
    if (t < TT) {
        float ft = (float)t;
        for (int d = w; d < DD; d += 4) {
            size_t ix = (size_t)(b * DD + d) * TT + t;
            float v = in[ix];
            float o = (v - mean) * rstd * g[d] + bia[d];
            if (add_pe) {
                float freq = expf((float)(d & ~1) * (-9.210340371976184f / 256.f));
                float ang = ft * freq;
                o += (d & 1) ? cosf(ang) : sinf(ang);
            }
            out[ix] = o;
            sq = fmaf(o, o, sq);
        }
    }
    __syncthreads();
    ps[w][lane] = sq;
    __syncthreads();
    if (w == 0 && t < TT) {
        float tot = ps[0][lane] + ps[1][lane] + ps[2][lane] + ps[3][lane];
        invn[b * TT + t] = 1.f / (sqrtf(tot) + 1e-8f);
    }
}

__device__ __forceinline__ float gelu_exact(float y) {
    return 0.5f * y * (1.f + erff(y * 0.7071067811865476f));
}

// ============ MFMA conv, diff-major: B-frag (Toeplitz) hoisted over 4-j groups ============
// D = t0-u0 is wave-uniform; one B-frag load (8 ds_read_b32) serves up to 4 j-members
// (3 MFMA each). Accumulation order per acc unchanged (u0 ascending) -> bit-identical.
#define XSTR 1032
__global__ __launch_bounds__(256) void k_conv_mfma(float* __restrict__ h, const float* __restrict__ kk,
                                                   const float* __restrict__ invn,
                                                   const float* __restrict__ s4D, int layer) {
    __shared__ unsigned short Xh[16 * XSTR], Xl[16 * XSTR];
    __shared__ unsigned int pkh[1040], pkl[1040];
    int d = blockIdx.x, b0 = blockIdx.y * 16;
    int tid = threadIdx.x;
    const float* krow = kk + (size_t)(layer * DD + d) * TT;
    for (int mm = tid; mm < 1040; mm += 256) {
        int m = mm - 32;
        float klo = (m >= 0 && m < TT) ? krow[m] : 0.f;
        float kpr = (m >= 1 && m <= TT) ? krow[m - 1] : 0.f;
        unsigned short lh = f2bf(klo); unsigned short ll = f2bf(klo - bf2f(lh));
        unsigned short ph = f2bf(kpr); unsigned short pl = f2bf(kpr - bf2f(ph));
        pkh[mm] = (unsigned int)lh | ((unsigned int)ph << 16);
        pkl[mm] = (unsigned int)ll | ((unsigned int)pl << 16);
    }
    for (int i = tid; i < 16 * 1024; i += 256) {
        int bb = i >> 10, t = i & 1023;
        float v = 0.f;
        if (t < TT)
            v = h[((size_t)(b0 + bb) * DD + d) * TT + t] * invn[(b0 + bb) * TT + t];
        unsigned short vh = f2bf(v);
        unsigned short vl = f2bf(v - bf2f(vh));
        Xh[bb * XSTR + t] = vh;
        Xl[bb * XSTR + t] = vl;
    }
    __syncthreads();
    float gate = 1.f / (1.f + expf(-s4D[layer * DD + d]));
    int wave = tid >> 6, lane = tid & 63;
    int tn = lane & 15, qq = lane >> 4;
    int Dmin = (wave & 1) ? 16 : 0;
    for (int g = 0; g < 4; ++g) {
        int j0 = wave + 16 * g;
        int j3 = j0 + 12;
        int j3e = (j3 > 62) ? (j3 - 4) : j3;   // drop j=63 (t0 >= TT)
        f32x4 acc[4][3];
#pragma unroll
        for (int m = 0; m < 4; ++m)
#pragma unroll
            for (int i = 0; i < 3; ++i) acc[m][i] = (f32x4){0.f, 0.f, 0.f, 0.f};
        for (int D = 16 * j3e; D >= Dmin; D -= 32) {
            int S32 = D + tn - 8 * qq + 32;
            union { bf16x8 v; unsigned int u[4]; } bh, bl;
            bh.u[0] = pkh[S32];     bl.u[0] = pkl[S32];
            bh.u[1] = pkh[S32 - 2]; bl.u[1] = pkl[S32 - 2];
            bh.u[2] = pkh[S32 - 4]; bl.u[2] = pkl[S32 - 4];
            bh.u[3] = pkh[S32 - 6]; bl.u[3] = pkl[S32 - 6];
#pragma unroll
            for (int m = 0; m < 4; ++m) {
                int jm = j0 + 4 * m;
                if (jm <= 62 && 16 * jm >= D) {
                    int u0 = 16 * jm - D;
                    const bf16x8 ah = *(const bf16x8*)&Xh[tn * XSTR + u0 + 8 * qq];
                    const bf16x8 al = *(const bf16x8*)&Xl[tn * XSTR + u0 + 8 * qq];
                    acc[m][0] = __builtin_amdgcn_mfma_f32_16x16x32_bf16(ah, bh.v, acc[m][0], 0, 0, 0);
                    acc[m][1] = __builtin_amdgcn_mfma_f32_16x16x32_bf16(ah, bl.v, acc[m][1], 0, 0, 0);
                    acc[m][2] = __builtin_amdgcn_mfma_f32_16x16x32_bf16(al, bh.v, acc[m][2], 0, 0, 0);
                }
            }
        }
#pragma unroll
        for (int m = 0; m < 4; ++m) {
            int jm = j0 + 4 * m;
            if (jm > 62) continue;
            int t = jm * 16 + tn;
            if (t < TT) {
#pragma unroll
                for (int r = 0; r < 4; ++r) {
                    int brow = 4 * qq + r;
                    size_t ix = ((size_t)(b0 + brow) * DD + d) * TT + t;
                    float y = acc[m][0][r] + acc[m][1][r] + acc[m][2][r];
                    float xn = bf2f(Xh[brow * XSTR + t]) + bf2f(Xl[brow * XSTR + t]);
                    float ho = xn / invn[(b0 + brow) * TT + t];
                    h[ix] = gelu_exact(y + xn * gate) + 1.1f * ho;
                }
            }
        }
    }
}

// ============ MHA pooling ============
__global__ __launch_bounds__(256) void k_qprep(const float* __restrict__ cls, const float* __restrict__ inw,
                                               const float* __restrict__ inb, float* __restrict__ qk,
                                               float* __restrict__ qb) {
    __shared__ float Qv[256];
    int j = threadIdx.x;
    float a = inb[j];
    for (int i = 0; i < 256; ++i) a = fmaf(inw[j * DD + i], cls[i], a);
    Qv[j] = a;
    __syncthreads();
    const float scale = 0.17677669529663687f; // 1/sqrt(32)
    for (int idx = threadIdx.x; idx < 8 * 256; idx += 256) {
        int hh = idx >> 8, i = idx & 255;
        float s = 0.f;
        for (int jj = 0; jj < 32; ++jj)
            s = fmaf(Qv[hh * 32 + jj], inw[(DD + hh * 32 + jj) * DD + i], s);
        qk[idx] = s * scale;
    }
    if (threadIdx.x < 8) {
        int hh = threadIdx.x;
        float s = 0.f;
        for (int jj = 0; jj < 32; ++jj)
            s = fmaf(Qv[hh * 32 + jj], inb[DD + hh * 32 + jj], s);
        qb[hh] = s * scale;
    }
}

__global__ __launch_bounds__(256) void k_scores(const float* __restrict__ h, const float* __restrict__ cls,
                                                const float* __restrict__ qkw, const float* __restrict__ qbw,
                                                float* __restrict__ sc) {
    __shared__ float qks[8 * 256];
    int b = blockIdx.y;
    int s = blockIdx.x * 256 + threadIdx.x;
    for (int i = threadIdx.x; i < 2048; i += 256) qks[i] = qkw[i];
    __syncthreads();
    if (s >= TT + 1) return;
    float acc[8];
#pragma unroll
    for (int hh = 0; hh < 8; ++hh) acc[hh] = qbw[hh];
    if (s == 0) {
        for (int i = 0; i < 256; ++i) {
            float v = cls[i];
#pragma unroll
            for (int hh = 0; hh < 8; ++hh) acc[hh] = fmaf(qks[hh * 256 + i], v, acc[hh]);
        }
    } else {
        const float* hb = h + (size_t)b * DD * TT + (s - 1);
        for (int i = 0; i < 256; ++i) {
            float v = hb[(size_t)i * TT];
#pragma unroll
            for (int hh = 0; hh < 8; ++hh) acc[hh] = fmaf(qks[hh * 256 + i], v, acc[hh]);
        }
    }
#pragma unroll
    for (int hh = 0; hh < 8; ++hh) sc[(size_t)(b * 8 + hh) * 1024 + s] = acc[hh];
}

__global__ __launch_bounds__(256) void k_softmax(const float* __restrict__ sc, float* __restrict__ att) {
    int row = blockIdx.x;
    const float* p = sc + (size_t)row * 1024;
    float* o = att + (size_t)row * 1024;
    __shared__ float red[256];
    float m = -3.4e38f;
    for (int s = threadIdx.x; s < TT + 1; s += 256) m = fmaxf(m, p[s]);
    red[threadIdx.x] = m; __syncthreads();
    for (int st = 128; st; st >>= 1) {
        if (threadIdx.x < st) red[threadIdx.x] = fmaxf(red[threadIdx.x], red[threadIdx.x + st]);
        __syncthreads();
    }
    m = red[0]; __syncthreads();
    float sum = 0.f;
    for (int s = threadIdx.x; s < TT + 1; s += 256) {
        float e = expf(p[s] - m);
        o[s] = e; sum += e;
    }
    red[threadIdx.x] = sum; __syncthreads();
    for (int st = 128; st; st >>= 1) {
        if (threadIdx.x < st) red[threadIdx.x] += red[threadIdx.x + st];
        __syncthreads();
    }
    float inv = 1.f / red[0];
    for (int s = threadIdx.x; s < TT + 1; s += 256) o[s] *= inv;
}

__global__ __launch_bounds__(256) void k_ctx(const float* __restrict__ h, const float* __restrict__ cls,
                                             const float* __restrict__ att, float* __restrict__ ctx) {
    __shared__ float as[8][1024];
    int b = blockIdx.y, i0 = blockIdx.x * 32;
    for (int idx = threadIdx.x; idx < 8 * 1024; idx += 256) {
        int hh = idx >> 10, s = idx & 1023;
        as[hh][s] = (s < TT + 1) ? att[(size_t)(b * 8 + hh) * 1024 + s] : 0.f;
    }
    __syncthreads();
    int w = threadIdx.x >> 6, lane = threadIdx.x & 63;
    for (int ii = 0; ii < 8; ++ii) {
        int i = i0 + w * 8 + ii;
        const float* hb = h + (size_t)(b * DD + i) * TT;
        float acc[8];
#pragma unroll
        for (int hh = 0; hh < 8; ++hh) acc[hh] = 0.f;
        for (int t = lane; t < TT; t += 64) {
            float v = hb[t];
#pragma unroll
            for (int hh = 0; hh < 8; ++hh) acc[hh] = fmaf(as[hh][t + 1], v, acc[hh]);
        }
#pragma unroll
        for (int off = 32; off; off >>= 1)
#pragma unroll
            for (int hh = 0; hh < 8; ++hh) acc[hh] += __shfl_down(acc[hh], off);
        if (lane == 0) {
#pragma unroll
            for (int hh = 0; hh < 8; ++hh)
                ctx[(size_t)(b * 8 + hh) * DD + i] = acc[hh] + as[hh][0] * cls[i];
        }
    }
}

__global__ __launch_bounds__(256) void k_head(const float* __restrict__ ctx, const float* __restrict__ inw,
                                              const float* __restrict__ inb, const float* __restrict__ outw,
                                              const float* __restrict__ outb, const float* __restrict__ w1,
                                              const float* __restrict__ b1, const float* __restrict__ w2,
                                              const float* __restrict__ b2, float* __restrict__ out) {
    int b = blockIdx.x;
    __shared__ float cs[2048], ao[256], po[256], hid[128];
    for (int i = threadIdx.x; i < 2048; i += 256) cs[i] = ctx[(size_t)b * 2048 + i];
    __syncthreads();
    int j = threadIdx.x;
    {
        int hh = j >> 5;
        float a = inb[2 * DD + j];
        const float* wv = inw + (size_t)(2 * DD + j) * DD;
        for (int i = 0; i < 256; ++i) a = fmaf(wv[i], cs[hh * 256 + i], a);
        ao[j] = a;
    }
    __syncthreads();
    {
        float a = outb[j];
        for (int i = 0; i < 256; ++i) a = fmaf(outw[j * DD + i], ao[i], a);
        po[j] = a;
    }
    __syncthreads();
    if (j < 128) {
        float a = b1[j];
        for (int i = 0; i < 256; ++i) a = fmaf(w1[j * 256 + i], po[i], a);
        hid[j] = fmaxf(a, 0.f);
    }
    __syncthreads();
    if (j == 0) {
        float a = b2[0];
        for (int i = 0; i < 128; ++i) a = fmaf(w2[i], hid[i], a);
        out[b] = a;
    }
}

extern "C" void kernel_launch(void* const* d_in, const int* in_sizes, int n_in,
                              void* d_out, int out_size, void* d_ws, size_t ws_size,
                              hipStream_t stream) {
    (void)in_sizes; (void)n_in; (void)out_size; (void)ws_size;
    const float* x        = (const float*)d_in[0];
    const float* w_in     = (const float*)d_in[1];
    const float* b_in     = (const float*)d_in[2];
    const float* ln_in_g  = (const float*)d_in[3];
    const float* ln_in_b  = (const float*)d_in[4];
    const float* s4B      = (const float*)d_in[5];
    const float* s4C      = (const float*)d_in[6];
    const float* s4logdt  = (const float*)d_in[7];
    const float* s4D      = (const float*)d_in[8];
    const float* ln_g     = (const float*)d_in[9];
    const float* ln_b     = (const float*)d_in[10];
    const float* cls      = (const float*)d_in[11];
    const float* mha_in_w = (const float*)d_in[12];
    const float* mha_in_b = (const float*)d_in[13];
    const float* mha_out_w= (const float*)d_in[14];
    const float* mha_out_b= (const float*)d_in[15];
    const float* head_w1  = (const float*)d_in[16];
    const float* head_b1  = (const float*)d_in[17];
    const float* head_w2  = (const float*)d_in[18];
    const float* head_b2  = (const float*)d_in[19];

    float* ws   = (float*)d_ws;
    float* h    = ws + OFF_H;
    float* kker = ws + OFF_K;
    float* invn = ws + OFF_INV;
    float* P  = h;
    float* Q  = h + 540672;
    float* Lb = h + 1064960;
    float* Rb = h + 3162112;
    float* qkb  = ws + OFF_MHA;
    float* qbb  = qkb + 2048;
    float* scb  = qbb + 16;
    float* attb = scb + 262144;
    float* ctxb = attb + 262144;
    unsigned short* whi = (unsigned short*)scb;
    unsigned short* wlo = whi + 256 * 136;

    k_wprep<<<dim3(256), dim3(64), 0, stream>>>(w_in, whi, wlo);
    k_build_ad<<<dim3(NLY), dim3(64), 0, stream>>>(s4logdt, P);
    for (int m = 1; m <= 5; ++m) {
        int half = 1 << (m - 1);
        k_mm64<<<dim3(half, NLY), dim3(256), 0, stream>>>(P, half, 33);
    }
    k_q_init<<<dim3(NLY), dim3(256), 0, stream>>>(P, Q);
    for (int m = 1; m <= 5; ++m) {
        int half = 1 << (m - 1);
        int cnt = (m == 5) ? 15 : half;
        k_mm64<<<dim3(cnt, NLY), dim3(256), 0, stream>>>(Q, half, 32);
    }
    k_lr<<<dim3(NLY * 64), dim3(256), 0, stream>>>(P, Q, s4B, s4C, Lb, Rb);
    k_kker<<<dim3(NLY * 256), dim3(256), 0, stream>>>(Lb, Rb, kker);

    k_embed_mfma<<<dim3(16, BB), dim3(256), 0, stream>>>(x, whi, wlo, w_in, b_in, h);
    k_ln<<<dim3(16, BB), dim3(256), 0, stream>>>(h, ln_in_g, ln_in_b, h, invn, 1);

    for (int l = 0; l < NLY; ++l) {
        k_conv_mfma<<<dim3(DD, 2), dim3(256), 0, stream>>>(h, kker, invn, s4D, l);
        k_ln<<<dim3(16, BB), dim3(256), 0, stream>>>(h, ln_g + l * DD, ln_b + l * DD, h, invn, 0);
    }

    k_qprep<<<dim3(1), dim3(256), 0, stream>>>(cls, mha_in_w, mha_in_b, qkb, qbb);
    k_scores<<<dim3(4, BB), dim3(256), 0, stream>>>(h, cls, qkb, qbb, scb);
    k_softmax<<<dim3(256), dim3(256), 0, stream>>>(scb, attb);
    k_ctx<<<dim3(8, BB), dim3(256), 0, stream>>>(h, cls, attb, ctxb);
    k_head<<<dim3(BB), dim3(256), 0, stream>>>(ctxb, mha_in_w, mha_in_b, mha_out_w, mha_out_b,
                                               head_w1, head_b1, head_w2, head_b2, (float*)d_out);
}